// Round 1
// baseline (512.212 us; speedup 1.0000x reference)
//
#include <hip/hip_runtime.h>
#include <hip/hip_bf16.h>

typedef unsigned short u16;
typedef unsigned long long u64;
typedef __bf16 bf16x8 __attribute__((ext_vector_type(8)));
typedef float f32x4 __attribute__((ext_vector_type(4)));

// ---------- helpers ----------
__device__ __forceinline__ void async16(const void* g, void* l) {
  __builtin_amdgcn_global_load_lds((const __attribute__((address_space(1))) void*)g,
                                   (__attribute__((address_space(3))) void*)l, 16, 0, 0);
}
__device__ __forceinline__ u16 f2bf(float f) {
  __hip_bfloat16 h = __float2bfloat16(f);
  u16 u; __builtin_memcpy(&u, &h, 2); return u;
}
__device__ __forceinline__ float bf2f(u16 u) {
  __hip_bfloat16 h; __builtin_memcpy(&h, &u, 2);
  return __bfloat162float(h);
}

// ---------- weight convert + pad (fp32 [R][C] -> bf16 [Rp][Cp], zero pad) ----------
__global__ __launch_bounds__(256) void convert_pad(const float* __restrict__ src,
                                                   u16* __restrict__ dst,
                                                   int R, int C, int Rp, int Cp) {
  int idx = blockIdx.x * 256 + threadIdx.x;
  int total = Rp * Cp;
  if (idx >= total) return;
  int r = idx / Cp, c = idx - r * Cp;
  float v = (r < R && c < C) ? src[(size_t)r * C + c] : 0.0f;
  dst[idx] = f2bf(v);
}

// ---------- x: fp32[32768][784] -> bf16[32768][800] (pad 0) + bits0[512][784] ----------
__global__ __launch_bounds__(256) void prep_x(const float* __restrict__ x,
                                              u16* __restrict__ xb,
                                              u64* __restrict__ bits0) {
  int tid = threadIdx.x, lane = tid & 63;
  int w = blockIdx.x * 4 + (tid >> 6);     // 0..6655 = 512 chunks * 13 fgroups
  int chunk = w / 13, g = w - chunk * 13;
  const float* xr = x + (size_t)(chunk * 64 + lane) * 784;
  u16* xo = xb + (size_t)(chunk * 64 + lane) * 800;
  u64 my = 0;
  int f0 = g * 64;
  int nq = (g == 12) ? 4 : 16;
  for (int qq = 0; qq < nq; qq++) {
    int f = f0 + qq * 4;
    float4 v = *(const float4*)(xr + f);
    ushort4 o;
    o.x = f2bf(v.x); o.y = f2bf(v.y); o.z = f2bf(v.z); o.w = f2bf(v.w);
    *(ushort4*)(xo + f) = o;
    u64 m0 = __ballot(v.x > 0.0f);
    u64 m1 = __ballot(v.y > 0.0f);
    u64 m2 = __ballot(v.z > 0.0f);
    u64 m3 = __ballot(v.w > 0.0f);
    int fl = qq * 4;
    if (lane == fl)     my = m0;
    if (lane == fl + 1) my = m1;
    if (lane == fl + 2) my = m2;
    if (lane == fl + 3) my = m3;
  }
  if (g == 12) {
    ushort4 z = {0, 0, 0, 0};
    *(ushort4*)(xo + 784) = z; *(ushort4*)(xo + 788) = z;
    *(ushort4*)(xo + 792) = z; *(ushort4*)(xo + 796) = z;
    if (lane < 16) bits0[(size_t)chunk * 784 + f0 + lane] = my;
  } else {
    bits0[(size_t)chunk * 784 + f0 + lane] = my;
  }
}

// ---------- bitpack bf16 h[32768][256] -> bits[512][256] ----------
__global__ __launch_bounds__(256) void bitpack_h(const u16* __restrict__ Hm,
                                                 u64* __restrict__ bits) {
  int tid = threadIdx.x, lane = tid & 63;
  int w = blockIdx.x * 4 + (tid >> 6);     // 0..2047 = 512 chunks * 4 fgroups
  int chunk = w >> 2, g = w & 3;
  const u16* hr = Hm + (size_t)(chunk * 64 + lane) * 256 + g * 64;
  u64 my = 0;
  #pragma unroll
  for (int qq = 0; qq < 16; qq++) {
    ushort4 v = *(const ushort4*)(hr + qq * 4);
    u64 m0 = __ballot(bf2f(v.x) > 0.0f);
    u64 m1 = __ballot(bf2f(v.y) > 0.0f);
    u64 m2 = __ballot(bf2f(v.z) > 0.0f);
    u64 m3 = __ballot(bf2f(v.w) > 0.0f);
    int fl = qq * 4;
    if (lane == fl)     my = m0;
    if (lane == fl + 1) my = m1;
    if (lane == fl + 2) my = m2;
    if (lane == fl + 3) my = m3;
  }
  bits[(size_t)chunk * 256 + g * 64 + lane] = my;
}

// ---------- bitpack logits fp32[32768][10] -> bits4[512][10] ----------
__global__ __launch_bounds__(256) void bitpack_logits(const float* __restrict__ L,
                                                      u64* __restrict__ bits4) {
  int tid = threadIdx.x, lane = tid & 63;
  int chunk = blockIdx.x * 4 + (tid >> 6);   // 0..511
  const float* lr = L + (size_t)(chunk * 64 + lane) * 10;
  u64 my = 0;
  #pragma unroll
  for (int c = 0; c < 10; c++) {
    u64 m = __ballot(lr[c] > 0.0f);
    if (lane == c) my = m;
  }
  if (lane < 10) bits4[(size_t)chunk * 10 + lane] = my;
}

// ---------- bf16 MFMA GEMM: Out = relu(A @ W^T + bias), A[M][K], W[N][K] ----------
__global__ __launch_bounds__(256) void gemm_relu(const u16* __restrict__ A,
                                                 const u16* __restrict__ W,
                                                 const float* __restrict__ bias,
                                                 u16* __restrict__ Out,
                                                 int M, int N, int K) {
  __shared__ __align__(16) u16 As[128 * 32];
  __shared__ __align__(16) u16 Bs[128 * 32];
  const int tid = threadIdx.x;
  const int m0 = blockIdx.x * 128, n0 = blockIdx.y * 128;
  const int row = tid >> 2, ko = (tid & 3) << 3;
  const u16* ag0 = A + (size_t)(m0 + row) * K + ko;
  const u16* ag1 = ag0 + (size_t)64 * K;
  const u16* bg0 = W + (size_t)(n0 + row) * K + ko;
  const u16* bg1 = bg0 + (size_t)64 * K;
  u16* al0 = As + tid * 8; u16* al1 = As + 2048 + tid * 8;
  u16* bl0 = Bs + tid * 8; u16* bl1 = Bs + 2048 + tid * 8;

  const int lane = tid & 63, wv = tid >> 6;
  const int wm = (wv & 1) * 64, wn = (wv >> 1) * 64;
  const int lm = lane & 15, q = lane >> 4;

  f32x4 acc[4][4] = {};
  const bf16x8* Af = (const bf16x8*)As;
  const bf16x8* Bf = (const bf16x8*)Bs;
  const int aidx = (wm + lm) * 4 + q;    // ((wm+mi*16+lm)*32 + q*8)/8, mi stride 64
  const int bidx = (wn + lm) * 4 + q;

  for (int k = 0; k < K; k += 32) {
    async16(ag0 + k, al0);
    async16(ag1 + k, al1);
    async16(bg0 + k, bl0);
    async16(bg1 + k, bl1);
    __syncthreads();
    bf16x8 a[4], b[4];
    #pragma unroll
    for (int i = 0; i < 4; i++) { a[i] = Af[aidx + i * 64]; b[i] = Bf[bidx + i * 64]; }
    #pragma unroll
    for (int mi = 0; mi < 4; mi++)
      #pragma unroll
      for (int ni = 0; ni < 4; ni++)
        acc[mi][ni] = __builtin_amdgcn_mfma_f32_16x16x32_bf16(a[mi], b[ni], acc[mi][ni], 0, 0, 0);
    __syncthreads();
  }

  #pragma unroll
  for (int ni = 0; ni < 4; ni++) {
    int n = n0 + wn + ni * 16 + lm;
    float bv = bias[n];
    #pragma unroll
    for (int mi = 0; mi < 4; mi++) {
      int m = m0 + wm + mi * 16 + q * 4;
      #pragma unroll
      for (int r = 0; r < 4; r++) {
        float h = acc[mi][ni][r] + bv;
        h = h > 0.0f ? h : 0.0f;
        Out[(size_t)(m + r) * N + n] = f2bf(h);
      }
    }
  }
}

// ---------- logits: fp32 Out[M][10] = A @ W4^T + b4, W4b bf16 [16][256] ----------
__global__ __launch_bounds__(256) void gemm_logits(const u16* __restrict__ A,
                                                   const u16* __restrict__ W,
                                                   const float* __restrict__ bias,
                                                   float* __restrict__ Out) {
  __shared__ __align__(16) u16 As[128 * 32];
  __shared__ __align__(16) u16 Bs[16 * 32];
  const int tid = threadIdx.x;
  const int m0 = blockIdx.x * 128;
  const int row = tid >> 2, ko = (tid & 3) << 3;
  const u16* ag0 = A + (size_t)(m0 + row) * 256 + ko;
  const u16* ag1 = ag0 + (size_t)64 * 256;
  u16* al0 = As + tid * 8; u16* al1 = As + 2048 + tid * 8;
  const u16* bg = W + (size_t)row * 256 + ko;   // only tid<64 valid (16 rows)
  u16* bl = Bs + tid * 8;

  const int lane = tid & 63, wv = tid >> 6;
  const int lm = lane & 15, q = lane >> 4;
  const int wm = wv * 32;

  f32x4 acc[2] = {};
  const bf16x8* Af = (const bf16x8*)As;
  const bf16x8* Bf = (const bf16x8*)Bs;

  for (int k = 0; k < 256; k += 32) {
    async16(ag0 + k, al0);
    async16(ag1 + k, al1);
    if (tid < 64) async16(bg + k, bl);
    __syncthreads();
    bf16x8 b = Bf[lm * 4 + q];
    #pragma unroll
    for (int mi = 0; mi < 2; mi++) {
      bf16x8 a = Af[(wm + mi * 16 + lm) * 4 + q];
      acc[mi] = __builtin_amdgcn_mfma_f32_16x16x32_bf16(a, b, acc[mi], 0, 0, 0);
    }
    __syncthreads();
  }

  int n = lm;
  if (n < 10) {
    float bv = bias[n];
    #pragma unroll
    for (int mi = 0; mi < 2; mi++) {
      #pragma unroll
      for (int r = 0; r < 4; r++) {
        int m = m0 + wm + mi * 16 + q * 4 + r;
        Out[(size_t)m * 10 + n] = acc[mi][r] + bv;
      }
    }
  }
}

// ---------- coactivation: C[FP][FC] += popcount over 64-chunk group ----------
__global__ __launch_bounds__(256) void coact(const u64* __restrict__ bp,
                                             const u64* __restrict__ bc,
                                             float* __restrict__ Cm,
                                             int FP, int FC) {
  __shared__ u64 Ps[16 * 64];
  __shared__ u64 Cs[16 * 64];
  const int tid = threadIdx.x;
  const int i0 = blockIdx.x * 64, j0 = blockIdx.y * 64, ch0 = blockIdx.z * 64;
  const int ti = tid >> 4, tj = tid & 15;
  unsigned cnt[4][4] = {};

  for (int s = 0; s < 4; s++) {
    int cb = ch0 + s * 16;
    #pragma unroll
    for (int r = 0; r < 4; r++) {
      int l = r * 256 + tid;
      int c = l >> 6, f = l & 63;
      Ps[l] = (i0 + f < FP) ? bp[(size_t)(cb + c) * FP + i0 + f] : 0ULL;
      Cs[l] = (j0 + f < FC) ? bc[(size_t)(cb + c) * FC + j0 + f] : 0ULL;
    }
    __syncthreads();
    #pragma unroll 4
    for (int c = 0; c < 16; c++) {
      u64 pv[4], cv[4];
      #pragma unroll
      for (int a = 0; a < 4; a++) pv[a] = Ps[c * 64 + ti * 4 + a];
      #pragma unroll
      for (int b = 0; b < 4; b++) cv[b] = Cs[c * 64 + tj * 4 + b];
      #pragma unroll
      for (int a = 0; a < 4; a++)
        #pragma unroll
        for (int b = 0; b < 4; b++)
          cnt[a][b] += (unsigned)__builtin_popcountll(pv[a] & cv[b]);
    }
    __syncthreads();
  }

  #pragma unroll
  for (int a = 0; a < 4; a++) {
    int i = i0 + ti * 4 + a;
    if (i >= FP) continue;
    #pragma unroll
    for (int b = 0; b < 4; b++) {
      int j = j0 + tj * 4 + b;
      if (j < FC) atomicAdd(&Cm[(size_t)i * FC + j], (float)cnt[a][b]);
    }
  }
}

// ---------- launch ----------
extern "C" void kernel_launch(void* const* d_in, const int* in_sizes, int n_in,
                              void* d_out, int out_size, void* d_ws, size_t ws_size,
                              hipStream_t stream) {
  const float* x  = (const float*)d_in[0];
  const float* W1 = (const float*)d_in[1];
  const float* b1 = (const float*)d_in[2];
  const float* W2 = (const float*)d_in[3];
  const float* b2 = (const float*)d_in[4];
  const float* W3 = (const float*)d_in[5];
  const float* b3 = (const float*)d_in[6];
  const float* W4 = (const float*)d_in[7];
  const float* b4 = (const float*)d_in[8];
  float* out = (float*)d_out;

  constexpr int B = 32768;
  constexpr size_t O_C0 = 327680, O_C1 = 528384, O_C2 = 593920, O_C3 = 659456;
  constexpr size_t O_END = 662016;

  char* ws = (char*)d_ws;
  u16* xb  = (u16*)(ws);                                  // 32768*800*2 = 52428800
  u16* h1b = (u16*)(ws + 52428800);                       // 16777216
  u16* h2b = (u16*)(ws + 52428800 + 16777216);            // 16777216
  u16* h3b = h1b;                                         // alias: h1 dead after bitpack1/gemm2
  char* wsp = ws + 52428800 + 2 * 16777216;
  u16* w1b = (u16*)(wsp);               wsp += 256 * 800 * 2;
  u16* w2b = (u16*)(wsp);               wsp += 256 * 256 * 2;
  u16* w3b = (u16*)(wsp);               wsp += 256 * 256 * 2;
  u16* w4b = (u16*)(wsp);               wsp += 16 * 256 * 2;
  u64* bits0 = (u64*)(wsp);             wsp += (size_t)512 * 784 * 8;
  u64* bits1 = (u64*)(wsp);             wsp += (size_t)512 * 256 * 8;
  u64* bits2 = (u64*)(wsp);             wsp += (size_t)512 * 256 * 8;
  u64* bits3 = (u64*)(wsp);             wsp += (size_t)512 * 256 * 8;
  u64* bits4 = (u64*)(wsp);             wsp += (size_t)512 * 10 * 8;

  // zero the coactivation output region (atomically accumulated)
  hipMemsetAsync((void*)(out + O_C0), 0, (O_END - O_C0) * sizeof(float), stream);

  // weight conversion
  convert_pad<<<800, 256, 0, stream>>>(W1, w1b, 256, 784, 256, 800);
  convert_pad<<<256, 256, 0, stream>>>(W2, w2b, 256, 256, 256, 256);
  convert_pad<<<256, 256, 0, stream>>>(W3, w3b, 256, 256, 256, 256);
  convert_pad<<<16, 256, 0, stream>>>(W4, w4b, 10, 256, 16, 256);

  // x -> bf16 (padded) + bits0
  prep_x<<<1664, 256, 0, stream>>>(x, xb, bits0);

  // layer 1..3
  gemm_relu<<<dim3(256, 2), 256, 0, stream>>>(xb, w1b, b1, h1b, B, 256, 800);
  bitpack_h<<<512, 256, 0, stream>>>(h1b, bits1);
  gemm_relu<<<dim3(256, 2), 256, 0, stream>>>(h1b, w2b, b2, h2b, B, 256, 256);
  bitpack_h<<<512, 256, 0, stream>>>(h2b, bits2);
  gemm_relu<<<dim3(256, 2), 256, 0, stream>>>(h2b, w3b, b3, h3b, B, 256, 256);
  bitpack_h<<<512, 256, 0, stream>>>(h3b, bits3);

  // logits + bits4
  gemm_logits<<<256, 256, 0, stream>>>(h3b, w4b, b4, out);
  bitpack_logits<<<128, 256, 0, stream>>>(out, bits4);

  // coactivations
  coact<<<dim3(13, 4, 8), 256, 0, stream>>>(bits0, bits1, out + O_C0, 784, 256);
  coact<<<dim3(4, 4, 8), 256, 0, stream>>>(bits1, bits2, out + O_C1, 256, 256);
  coact<<<dim3(4, 4, 8), 256, 0, stream>>>(bits2, bits3, out + O_C2, 256, 256);
  coact<<<dim3(4, 1, 8), 256, 0, stream>>>(bits3, bits4, out + O_C3, 256, 10);
}

// Round 2
// 374.610 us; speedup vs baseline: 1.3673x; 1.3673x over previous
//
#include <hip/hip_runtime.h>
#include <hip/hip_bf16.h>

typedef unsigned short u16;
typedef unsigned long long u64;
typedef __bf16 bf16x8 __attribute__((ext_vector_type(8)));
typedef float f32x4 __attribute__((ext_vector_type(4)));

// ---------- helpers ----------
__device__ __forceinline__ void async16(const void* g, void* l) {
  __builtin_amdgcn_global_load_lds((const __attribute__((address_space(1))) void*)g,
                                   (__attribute__((address_space(3))) void*)l, 16, 0, 0);
}
__device__ __forceinline__ u16 f2bf(float f) {
  __hip_bfloat16 h = __float2bfloat16(f);
  u16 u; __builtin_memcpy(&u, &h, 2); return u;
}

// ---------- weight convert + pad (fp32 [R][C] -> bf16 [Rp][Cp], zero pad) ----------
__global__ __launch_bounds__(256) void convert_pad(const float* __restrict__ src,
                                                   u16* __restrict__ dst,
                                                   int R, int C, int Rp, int Cp) {
  int idx = blockIdx.x * 256 + threadIdx.x;
  int total = Rp * Cp;
  if (idx >= total) return;
  int r = idx / Cp, c = idx - r * Cp;
  float v = (r < R && c < C) ? src[(size_t)r * C + c] : 0.0f;
  dst[idx] = f2bf(v);
}

// ---------- x: coalesced tile convert fp32[32768][784]->bf16[32768][800] + bits0 ----------
// grid (13, 512): blockIdx.x = 64-col group (last=16 cols + pad), blockIdx.y = row chunk
__global__ __launch_bounds__(256) void prep_x(const float* __restrict__ x,
                                              u16* __restrict__ xb,
                                              u64* __restrict__ bits0) {
  __shared__ u16 S[64 * 66];     // sign predicates, stride 66 u16 -> 2-way banks (free)
  const int t = threadIdx.x;
  const int g = blockIdx.x;      // 0..12
  const int chunk = blockIdx.y;  // 0..511
  const int row0 = chunk * 64, col0 = g * 64;

  if (g < 12) {
    #pragma unroll
    for (int i = 0; i < 4; i++) {
      int idx = i * 256 + t;
      int r = idx >> 4, c4 = (idx & 15) * 4;
      float4 v = *(const float4*)(x + (size_t)(row0 + r) * 784 + col0 + c4);
      ushort4 o;
      o.x = f2bf(v.x); o.y = f2bf(v.y); o.z = f2bf(v.z); o.w = f2bf(v.w);
      *(ushort4*)(xb + (size_t)(row0 + r) * 800 + col0 + c4) = o;
      S[r * 66 + c4]     = v.x > 0.0f;
      S[r * 66 + c4 + 1] = v.y > 0.0f;
      S[r * 66 + c4 + 2] = v.z > 0.0f;
      S[r * 66 + c4 + 3] = v.w > 0.0f;
    }
  } else {
    // 16 real cols (768..783) + 16 pad cols (784..799)
    int r = t >> 2, c4 = (t & 3) * 4;
    float4 v = *(const float4*)(x + (size_t)(row0 + r) * 784 + col0 + c4);
    ushort4 o;
    o.x = f2bf(v.x); o.y = f2bf(v.y); o.z = f2bf(v.z); o.w = f2bf(v.w);
    *(ushort4*)(xb + (size_t)(row0 + r) * 800 + col0 + c4) = o;
    ushort4 z = {0, 0, 0, 0};
    *(ushort4*)(xb + (size_t)(row0 + r) * 800 + 784 + c4) = z;
    S[r * 66 + c4]     = v.x > 0.0f;
    S[r * 66 + c4 + 1] = v.y > 0.0f;
    S[r * 66 + c4 + 2] = v.z > 0.0f;
    S[r * 66 + c4 + 3] = v.w > 0.0f;
  }
  __syncthreads();

  const int lane = t & 63, wv = t >> 6;
  const int ncols = (g < 12) ? 64 : 16;
  const int cbase = wv * 16;
  if (cbase < ncols) {
    u64 my = 0;
    #pragma unroll
    for (int i = 0; i < 16; i++) {
      u64 m = __ballot(S[lane * 66 + cbase + i] != 0);
      if (lane == i) my = m;
    }
    if (lane < 16) bits0[(size_t)chunk * 784 + col0 + cbase + lane] = my;
  }
}

// ---------- coalesced bitpack bf16 h[32768][256] -> bits[512][256] ----------
// grid (4, 512). ReLU'd bf16: >0  <=>  raw bits != 0.
__global__ __launch_bounds__(256) void bitpack_h(const u16* __restrict__ Hm,
                                                 u64* __restrict__ bits) {
  __shared__ u16 S[64 * 66];
  const int t = threadIdx.x;
  const int g = blockIdx.x;      // 0..3
  const int chunk = blockIdx.y;  // 0..511
  const int row0 = chunk * 64, col0 = g * 64;
  #pragma unroll
  for (int i = 0; i < 4; i++) {
    int idx = i * 256 + t;
    int r = idx >> 4, c4 = (idx & 15) * 4;
    ushort4 v = *(const ushort4*)(Hm + (size_t)(row0 + r) * 256 + col0 + c4);
    S[r * 66 + c4]     = v.x;
    S[r * 66 + c4 + 1] = v.y;
    S[r * 66 + c4 + 2] = v.z;
    S[r * 66 + c4 + 3] = v.w;
  }
  __syncthreads();
  const int lane = t & 63, wv = t >> 6;
  const int cbase = wv * 16;
  u64 my = 0;
  #pragma unroll
  for (int i = 0; i < 16; i++) {
    u64 m = __ballot(S[lane * 66 + cbase + i] != 0);
    if (lane == i) my = m;
  }
  if (lane < 16) bits[(size_t)chunk * 256 + col0 + cbase + lane] = my;
}

// ---------- bitpack logits fp32[32768][10] -> bits4[512][10] ----------
__global__ __launch_bounds__(256) void bitpack_logits(const float* __restrict__ L,
                                                      u64* __restrict__ bits4) {
  int tid = threadIdx.x, lane = tid & 63;
  int chunk = blockIdx.x * 4 + (tid >> 6);   // 0..511
  const float* lr = L + (size_t)(chunk * 64 + lane) * 10;
  u64 my = 0;
  #pragma unroll
  for (int c = 0; c < 10; c++) {
    u64 m = __ballot(lr[c] > 0.0f);
    if (lane == c) my = m;
  }
  if (lane < 10) bits4[(size_t)chunk * 10 + lane] = my;
}

// ---------- bf16 MFMA GEMM: Out = relu(A @ W^T + bias), A[M][K], W[N][K] ----------
__global__ __launch_bounds__(256) void gemm_relu(const u16* __restrict__ A,
                                                 const u16* __restrict__ W,
                                                 const float* __restrict__ bias,
                                                 u16* __restrict__ Out,
                                                 int M, int N, int K) {
  __shared__ __align__(16) u16 As[128 * 32];
  __shared__ __align__(16) u16 Bs[128 * 32];
  const int tid = threadIdx.x;
  const int m0 = blockIdx.x * 128, n0 = blockIdx.y * 128;
  const int row = tid >> 2, ko = (tid & 3) << 3;
  const u16* ag0 = A + (size_t)(m0 + row) * K + ko;
  const u16* ag1 = ag0 + (size_t)64 * K;
  const u16* bg0 = W + (size_t)(n0 + row) * K + ko;
  const u16* bg1 = bg0 + (size_t)64 * K;
  u16* al0 = As + tid * 8; u16* al1 = As + 2048 + tid * 8;
  u16* bl0 = Bs + tid * 8; u16* bl1 = Bs + 2048 + tid * 8;

  const int lane = tid & 63, wv = tid >> 6;
  const int wm = (wv & 1) * 64, wn = (wv >> 1) * 64;
  const int lm = lane & 15, q = lane >> 4;

  f32x4 acc[4][4] = {};
  const bf16x8* Af = (const bf16x8*)As;
  const bf16x8* Bf = (const bf16x8*)Bs;
  const int aidx = (wm + lm) * 4 + q;
  const int bidx = (wn + lm) * 4 + q;

  for (int k = 0; k < K; k += 32) {
    async16(ag0 + k, al0);
    async16(ag1 + k, al1);
    async16(bg0 + k, bl0);
    async16(bg1 + k, bl1);
    __syncthreads();
    bf16x8 a[4], b[4];
    #pragma unroll
    for (int i = 0; i < 4; i++) { a[i] = Af[aidx + i * 64]; b[i] = Bf[bidx + i * 64]; }
    #pragma unroll
    for (int mi = 0; mi < 4; mi++)
      #pragma unroll
      for (int ni = 0; ni < 4; ni++)
        acc[mi][ni] = __builtin_amdgcn_mfma_f32_16x16x32_bf16(a[mi], b[ni], acc[mi][ni], 0, 0, 0);
    __syncthreads();
  }

  #pragma unroll
  for (int ni = 0; ni < 4; ni++) {
    int n = n0 + wn + ni * 16 + lm;
    float bv = bias[n];
    #pragma unroll
    for (int mi = 0; mi < 4; mi++) {
      int m = m0 + wm + mi * 16 + q * 4;
      #pragma unroll
      for (int r = 0; r < 4; r++) {
        float h = acc[mi][ni][r] + bv;
        h = h > 0.0f ? h : 0.0f;
        Out[(size_t)(m + r) * N + n] = f2bf(h);
      }
    }
  }
}

// ---------- logits: fp32 Out[M][10] = A @ W4^T + b4, W4b bf16 [16][256] ----------
__global__ __launch_bounds__(256) void gemm_logits(const u16* __restrict__ A,
                                                   const u16* __restrict__ W,
                                                   const float* __restrict__ bias,
                                                   float* __restrict__ Out) {
  __shared__ __align__(16) u16 As[128 * 32];
  __shared__ __align__(16) u16 Bs[16 * 32];
  const int tid = threadIdx.x;
  const int m0 = blockIdx.x * 128;
  const int row = tid >> 2, ko = (tid & 3) << 3;
  const u16* ag0 = A + (size_t)(m0 + row) * 256 + ko;
  const u16* ag1 = ag0 + (size_t)64 * 256;
  u16* al0 = As + tid * 8; u16* al1 = As + 2048 + tid * 8;
  const u16* bg = W + (size_t)row * 256 + ko;   // only tid<64 valid (16 rows)
  u16* bl = Bs + tid * 8;

  const int lane = tid & 63, wv = tid >> 6;
  const int lm = lane & 15, q = lane >> 4;
  const int wm = wv * 32;

  f32x4 acc[2] = {};
  const bf16x8* Af = (const bf16x8*)As;
  const bf16x8* Bf = (const bf16x8*)Bs;

  for (int k = 0; k < 256; k += 32) {
    async16(ag0 + k, al0);
    async16(ag1 + k, al1);
    if (tid < 64) async16(bg + k, bl);
    __syncthreads();
    bf16x8 b = Bf[lm * 4 + q];
    #pragma unroll
    for (int mi = 0; mi < 2; mi++) {
      bf16x8 a = Af[(wm + mi * 16 + lm) * 4 + q];
      acc[mi] = __builtin_amdgcn_mfma_f32_16x16x32_bf16(a, b, acc[mi], 0, 0, 0);
    }
    __syncthreads();
  }

  int n = lm;
  if (n < 10) {
    float bv = bias[n];
    #pragma unroll
    for (int mi = 0; mi < 2; mi++) {
      #pragma unroll
      for (int r = 0; r < 4; r++) {
        int m = m0 + wm + mi * 16 + q * 4 + r;
        Out[(size_t)m * 10 + n] = acc[mi][r] + bv;
      }
    }
  }
}

// ---------- coactivation: C[FP][FC] += popcount over 64-chunk group ----------
__global__ __launch_bounds__(256) void coact(const u64* __restrict__ bp,
                                             const u64* __restrict__ bc,
                                             float* __restrict__ Cm,
                                             int FP, int FC) {
  __shared__ u64 Ps[16 * 64];
  __shared__ u64 Cs[16 * 64];
  const int tid = threadIdx.x;
  const int i0 = blockIdx.x * 64, j0 = blockIdx.y * 64, ch0 = blockIdx.z * 64;
  const int ti = tid >> 4, tj = tid & 15;
  unsigned cnt[4][4] = {};

  for (int s = 0; s < 4; s++) {
    int cb = ch0 + s * 16;
    #pragma unroll
    for (int r = 0; r < 4; r++) {
      int l = r * 256 + tid;
      int c = l >> 6, f = l & 63;
      Ps[l] = (i0 + f < FP) ? bp[(size_t)(cb + c) * FP + i0 + f] : 0ULL;
      Cs[l] = (j0 + f < FC) ? bc[(size_t)(cb + c) * FC + j0 + f] : 0ULL;
    }
    __syncthreads();
    #pragma unroll 4
    for (int c = 0; c < 16; c++) {
      u64 pv[4], cv[4];
      #pragma unroll
      for (int a = 0; a < 4; a++) pv[a] = Ps[c * 64 + ti * 4 + a];
      #pragma unroll
      for (int b = 0; b < 4; b++) cv[b] = Cs[c * 64 + tj * 4 + b];
      #pragma unroll
      for (int a = 0; a < 4; a++)
        #pragma unroll
        for (int b = 0; b < 4; b++)
          cnt[a][b] += (unsigned)__builtin_popcountll(pv[a] & cv[b]);
    }
    __syncthreads();
  }

  #pragma unroll
  for (int a = 0; a < 4; a++) {
    int i = i0 + ti * 4 + a;
    if (i >= FP) continue;
    #pragma unroll
    for (int b = 0; b < 4; b++) {
      int j = j0 + tj * 4 + b;
      if (j < FC) atomicAdd(&Cm[(size_t)i * FC + j], (float)cnt[a][b]);
    }
  }
}

// ---------- launch ----------
extern "C" void kernel_launch(void* const* d_in, const int* in_sizes, int n_in,
                              void* d_out, int out_size, void* d_ws, size_t ws_size,
                              hipStream_t stream) {
  const float* x  = (const float*)d_in[0];
  const float* W1 = (const float*)d_in[1];
  const float* b1 = (const float*)d_in[2];
  const float* W2 = (const float*)d_in[3];
  const float* b2 = (const float*)d_in[4];
  const float* W3 = (const float*)d_in[5];
  const float* b3 = (const float*)d_in[6];
  const float* W4 = (const float*)d_in[7];
  const float* b4 = (const float*)d_in[8];
  float* out = (float*)d_out;

  constexpr int B = 32768;
  constexpr size_t O_C0 = 327680, O_C1 = 528384, O_C2 = 593920, O_C3 = 659456;
  constexpr size_t O_END = 662016;

  char* ws = (char*)d_ws;
  u16* xb  = (u16*)(ws);                                  // 32768*800*2
  u16* h1b = (u16*)(ws + 52428800);
  u16* h2b = (u16*)(ws + 52428800 + 16777216);
  u16* h3b = h1b;                                         // alias: h1 dead after bitpack1/gemm2
  char* wsp = ws + 52428800 + 2 * 16777216;
  u16* w1b = (u16*)(wsp);               wsp += 256 * 800 * 2;
  u16* w2b = (u16*)(wsp);               wsp += 256 * 256 * 2;
  u16* w3b = (u16*)(wsp);               wsp += 256 * 256 * 2;
  u16* w4b = (u16*)(wsp);               wsp += 16 * 256 * 2;
  u64* bits0 = (u64*)(wsp);             wsp += (size_t)512 * 784 * 8;
  u64* bits1 = (u64*)(wsp);             wsp += (size_t)512 * 256 * 8;
  u64* bits2 = (u64*)(wsp);             wsp += (size_t)512 * 256 * 8;
  u64* bits3 = (u64*)(wsp);             wsp += (size_t)512 * 256 * 8;
  u64* bits4 = (u64*)(wsp);             wsp += (size_t)512 * 10 * 8;

  hipMemsetAsync((void*)(out + O_C0), 0, (O_END - O_C0) * sizeof(float), stream);

  convert_pad<<<800, 256, 0, stream>>>(W1, w1b, 256, 784, 256, 800);
  convert_pad<<<256, 256, 0, stream>>>(W2, w2b, 256, 256, 256, 256);
  convert_pad<<<256, 256, 0, stream>>>(W3, w3b, 256, 256, 256, 256);
  convert_pad<<<16, 256, 0, stream>>>(W4, w4b, 10, 256, 16, 256);

  prep_x<<<dim3(13, 512), 256, 0, stream>>>(x, xb, bits0);

  gemm_relu<<<dim3(256, 2), 256, 0, stream>>>(xb, w1b, b1, h1b, B, 256, 800);
  bitpack_h<<<dim3(4, 512), 256, 0, stream>>>(h1b, bits1);
  gemm_relu<<<dim3(256, 2), 256, 0, stream>>>(h1b, w2b, b2, h2b, B, 256, 256);
  bitpack_h<<<dim3(4, 512), 256, 0, stream>>>(h2b, bits2);
  gemm_relu<<<dim3(256, 2), 256, 0, stream>>>(h2b, w3b, b3, h3b, B, 256, 256);
  bitpack_h<<<dim3(4, 512), 256, 0, stream>>>(h3b, bits3);

  gemm_logits<<<256, 256, 0, stream>>>(h3b, w4b, b4, out);
  bitpack_logits<<<128, 256, 0, stream>>>(out, bits4);

  coact<<<dim3(13, 4, 8), 256, 0, stream>>>(bits0, bits1, out + O_C0, 784, 256);
  coact<<<dim3(4, 4, 8), 256, 0, stream>>>(bits1, bits2, out + O_C1, 256, 256);
  coact<<<dim3(4, 4, 8), 256, 0, stream>>>(bits2, bits3, out + O_C2, 256, 256);
  coact<<<dim3(4, 1, 8), 256, 0, stream>>>(bits3, bits4, out + O_C3, 256, 10);
}

// Round 3
// 361.424 us; speedup vs baseline: 1.4172x; 1.0365x over previous
//
#include <hip/hip_runtime.h>
#include <hip/hip_bf16.h>

typedef unsigned short u16;
typedef unsigned long long u64;
typedef __bf16 bf16x8 __attribute__((ext_vector_type(8)));
typedef float f32x4 __attribute__((ext_vector_type(4)));

// ---------- helpers ----------
__device__ __forceinline__ void async16(const void* g, void* l) {
  __builtin_amdgcn_global_load_lds((const __attribute__((address_space(1))) void*)g,
                                   (__attribute__((address_space(3))) void*)l, 16, 0, 0);
}
__device__ __forceinline__ u16 f2bf(float f) {
  __hip_bfloat16 h = __float2bfloat16(f);
  u16 u; __builtin_memcpy(&u, &h, 2); return u;
}

// ---------- weight convert + pad (fp32 [R][C] -> bf16 [Rp][Cp], zero pad) ----------
__global__ __launch_bounds__(256) void convert_pad(const float* __restrict__ src,
                                                   u16* __restrict__ dst,
                                                   int R, int C, int Rp, int Cp) {
  int idx = blockIdx.x * 256 + threadIdx.x;
  int total = Rp * Cp;
  if (idx >= total) return;
  int r = idx / Cp, c = idx - r * Cp;
  float v = (r < R && c < C) ? src[(size_t)r * C + c] : 0.0f;
  dst[idx] = f2bf(v);
}

// ---------- x: coalesced tile convert fp32[32768][784]->bf16[32768][800] + bits0 ----------
__global__ __launch_bounds__(256) void prep_x(const float* __restrict__ x,
                                              u16* __restrict__ xb,
                                              u64* __restrict__ bits0) {
  __shared__ u16 S[64 * 66];
  const int t = threadIdx.x;
  const int g = blockIdx.x;      // 0..12
  const int chunk = blockIdx.y;  // 0..511
  const int row0 = chunk * 64, col0 = g * 64;

  if (g < 12) {
    #pragma unroll
    for (int i = 0; i < 4; i++) {
      int idx = i * 256 + t;
      int r = idx >> 4, c4 = (idx & 15) * 4;
      float4 v = *(const float4*)(x + (size_t)(row0 + r) * 784 + col0 + c4);
      ushort4 o;
      o.x = f2bf(v.x); o.y = f2bf(v.y); o.z = f2bf(v.z); o.w = f2bf(v.w);
      *(ushort4*)(xb + (size_t)(row0 + r) * 800 + col0 + c4) = o;
      S[r * 66 + c4]     = v.x > 0.0f;
      S[r * 66 + c4 + 1] = v.y > 0.0f;
      S[r * 66 + c4 + 2] = v.z > 0.0f;
      S[r * 66 + c4 + 3] = v.w > 0.0f;
    }
  } else {
    int r = t >> 2, c4 = (t & 3) * 4;
    float4 v = *(const float4*)(x + (size_t)(row0 + r) * 784 + col0 + c4);
    ushort4 o;
    o.x = f2bf(v.x); o.y = f2bf(v.y); o.z = f2bf(v.z); o.w = f2bf(v.w);
    *(ushort4*)(xb + (size_t)(row0 + r) * 800 + col0 + c4) = o;
    ushort4 z = {0, 0, 0, 0};
    *(ushort4*)(xb + (size_t)(row0 + r) * 800 + 784 + c4) = z;
    S[r * 66 + c4]     = v.x > 0.0f;
    S[r * 66 + c4 + 1] = v.y > 0.0f;
    S[r * 66 + c4 + 2] = v.z > 0.0f;
    S[r * 66 + c4 + 3] = v.w > 0.0f;
  }
  __syncthreads();

  const int lane = t & 63, wv = t >> 6;
  const int ncols = (g < 12) ? 64 : 16;
  const int cbase = wv * 16;
  if (cbase < ncols) {
    u64 my = 0;
    #pragma unroll
    for (int i = 0; i < 16; i++) {
      u64 m = __ballot(S[lane * 66 + cbase + i] != 0);
      if (lane == i) my = m;
    }
    if (lane < 16) bits0[(size_t)chunk * 784 + col0 + cbase + lane] = my;
  }
}

// ---------- fully-fused forward: 128 rows per block, h resident in LDS ----------
__global__ __launch_bounds__(256, 1) void fwd_fused(
    const u16* __restrict__ xb,
    const u16* __restrict__ W1b, const float* __restrict__ b1,
    const u16* __restrict__ W2b, const float* __restrict__ b2,
    const u16* __restrict__ W3b, const float* __restrict__ b3,
    const u16* __restrict__ W4b, const float* __restrict__ b4,
    float* __restrict__ out,
    u64* __restrict__ bits1, u64* __restrict__ bits2,
    u64* __restrict__ bits3, u64* __restrict__ bits4) {

  __shared__ __align__(16) u16 hbuf[8 * 4096];   // h as 8 tiles [kc][128][32] = 64 KB
  __shared__ __align__(16) u16 Wt[2][8192];      // W tile dbuf: 256x32 bf16 x2 = 32 KB
  __shared__ __align__(16) u16 At[2][4096];      // A tile dbuf (layer1): 128x32 x2 = 16 KB

  const int tid = threadIdx.x;
  const int lane = tid & 63, wv = tid >> 6;
  const int lm = lane & 15, q = lane >> 4;
  const int m0 = blockIdx.x * 128;
  const int wm = (wv & 1) * 64, wn = (wv >> 1) * 128;

  // stage a 256x32 W tile (16 KB) for k-chunk kc
  auto stageW = [&](const u16* W, int K, int kc, u16* dst) {
    #pragma unroll
    for (int i = 0; i < 4; i++) {
      int seg = i * 256 + tid;
      int n = seg >> 2, kq = seg & 3;
      async16(W + (size_t)n * K + kc * 32 + kq * 8, dst + seg * 8);
    }
  };
  // stage a 128x32 A tile (8 KB) from xb (K=800) for k-chunk kc
  auto stageA1 = [&](int kc, u16* dst) {
    #pragma unroll
    for (int i = 0; i < 2; i++) {
      int seg = i * 256 + tid;
      int r = seg >> 2, kq = seg & 3;
      async16(xb + (size_t)(m0 + r) * 800 + kc * 32 + kq * 8, dst + seg * 8);
    }
  };
  // epilogue: acc -> bias+relu -> bf16 -> hbuf tiles
  auto epilogue = [&](f32x4 (&acc)[4][8], const float* __restrict__ bias) {
    #pragma unroll
    for (int ni = 0; ni < 8; ni++) {
      int col = wn + ni * 16 + lm;
      float bv = bias[col];
      int kt = col >> 5, cl = col & 31;
      #pragma unroll
      for (int mi = 0; mi < 4; mi++) {
        #pragma unroll
        for (int r = 0; r < 4; r++) {
          int row = wm + mi * 16 + q * 4 + r;
          float h = acc[mi][ni][r] + bv;
          h = h > 0.0f ? h : 0.0f;
          hbuf[kt * 4096 + row * 32 + cl] = f2bf(h);
        }
      }
    }
  };
  // ballot-pack hbuf (ReLU'd bf16: >0 <=> bits != 0) -> bits[chunk][256]
  auto ballot_bits = [&](u64* bits) {
    const int chunk = wv & 1;
    const int k0 = (wv >> 1) * 4;
    const int row = chunk * 64 + lane;
    #pragma unroll
    for (int kk = 0; kk < 4; kk++) {
      int kt = k0 + kk;
      union { uint4 v[4]; u16 s[32]; } u;
      #pragma unroll
      for (int j = 0; j < 4; j++) u.v[j] = ((const uint4*)hbuf)[kt * 512 + row * 4 + j];
      u64 my = 0;
      #pragma unroll
      for (int c = 0; c < 32; c++) {
        u64 m = __ballot(u.s[c] != 0);
        if (lane == c) my = m;
      }
      if (lane < 32) bits[(size_t)(blockIdx.x * 2 + chunk) * 256 + kt * 32 + lane] = my;
    }
  };

  // ---- layer 1: K=800, A from xb ----
  {
    f32x4 acc[4][8] = {};
    stageA1(0, At[0]);
    stageW(W1b, 800, 0, Wt[0]);
    for (int kc = 0; kc < 25; kc++) {
      int cur = kc & 1;
      __syncthreads();   // drains this k-step's staging (prefetched during prev compute)
      if (kc + 1 < 25) { stageA1(kc + 1, At[1 - cur]); stageW(W1b, 800, kc + 1, Wt[1 - cur]); }
      const bf16x8* Av = (const bf16x8*)At[cur];
      const bf16x8* Bv = (const bf16x8*)Wt[cur];
      bf16x8 a[4], b[8];
      #pragma unroll
      for (int mi = 0; mi < 4; mi++) a[mi] = Av[(wm + mi * 16 + lm) * 4 + q];
      #pragma unroll
      for (int ni = 0; ni < 8; ni++) b[ni] = Bv[(wn + ni * 16 + lm) * 4 + q];
      #pragma unroll
      for (int mi = 0; mi < 4; mi++)
        #pragma unroll
        for (int ni = 0; ni < 8; ni++)
          acc[mi][ni] = __builtin_amdgcn_mfma_f32_16x16x32_bf16(a[mi], b[ni], acc[mi][ni], 0, 0, 0);
    }
    __syncthreads();
    epilogue(acc, b1);
  }
  __syncthreads();
  ballot_bits(bits1);

  // ---- layers 2 and 3: K=256, A from hbuf ----
  auto layer256 = [&](const u16* W, const float* __restrict__ bias, u64* bits) {
    f32x4 acc[4][8] = {};
    stageW(W, 256, 0, Wt[0]);
    for (int kc = 0; kc < 8; kc++) {
      int cur = kc & 1;
      __syncthreads();
      if (kc + 1 < 8) stageW(W, 256, kc + 1, Wt[1 - cur]);
      const bf16x8* Hv = (const bf16x8*)hbuf;
      const bf16x8* Bv = (const bf16x8*)Wt[cur];
      bf16x8 a[4], b[8];
      #pragma unroll
      for (int mi = 0; mi < 4; mi++) a[mi] = Hv[kc * 512 + (wm + mi * 16 + lm) * 4 + q];
      #pragma unroll
      for (int ni = 0; ni < 8; ni++) b[ni] = Bv[(wn + ni * 16 + lm) * 4 + q];
      #pragma unroll
      for (int mi = 0; mi < 4; mi++)
        #pragma unroll
        for (int ni = 0; ni < 8; ni++)
          acc[mi][ni] = __builtin_amdgcn_mfma_f32_16x16x32_bf16(a[mi], b[ni], acc[mi][ni], 0, 0, 0);
    }
    __syncthreads();     // all reads of h_prev complete before overwrite
    epilogue(acc, bias);
    __syncthreads();
    ballot_bits(bits);
  };
  layer256(W2b, b2, bits2);
  layer256(W3b, b3, bits3);

  // ---- logits: K=256, N=10 (W4b padded to 16x256), fp32 out + bits4 ----
  {
    #pragma unroll
    for (int i = 0; i < 2; i++) {
      int seg = i * 256 + tid;
      async16(W4b + seg * 8, Wt[0] + seg * 8);    // whole 8 KB W4
    }
    __syncthreads();
    f32x4 acc[2] = {};
    const bf16x8* Hv = (const bf16x8*)hbuf;
    const bf16x8* Bv = (const bf16x8*)Wt[0];
    #pragma unroll
    for (int kc = 0; kc < 8; kc++) {
      bf16x8 b = Bv[lm * 32 + kc * 4 + q];
      #pragma unroll
      for (int mi = 0; mi < 2; mi++) {
        bf16x8 a = Hv[kc * 512 + (wv * 32 + mi * 16 + lm) * 4 + q];
        acc[mi] = __builtin_amdgcn_mfma_f32_16x16x32_bf16(a, b, acc[mi], 0, 0, 0);
      }
    }
    float* Ls = (float*)At;                       // 128 x 17 fp32 scratch
    float bv = (lm < 10) ? b4[lm] : 0.0f;
    #pragma unroll
    for (int mi = 0; mi < 2; mi++) {
      #pragma unroll
      for (int r = 0; r < 4; r++) {
        int row = wv * 32 + mi * 16 + q * 4 + r;
        float v = acc[mi][r] + bv;
        Ls[row * 17 + lm] = v;
        if (lm < 10) out[(size_t)(m0 + row) * 10 + lm] = v;
      }
    }
    __syncthreads();
    if (wv < 2) {
      int row = wv * 64 + lane;
      u64 my = 0;
      #pragma unroll
      for (int c = 0; c < 10; c++) {
        u64 m = __ballot(Ls[row * 17 + c] > 0.0f);
        if (lane == c) my = m;
      }
      if (lane < 10) bits4[(size_t)(blockIdx.x * 2 + wv) * 10 + lane] = my;
    }
  }
}

// ---------- coactivation: C[FP][FC] += popcount over 64-chunk group ----------
__global__ __launch_bounds__(256) void coact(const u64* __restrict__ bp,
                                             const u64* __restrict__ bc,
                                             float* __restrict__ Cm,
                                             int FP, int FC) {
  __shared__ u64 Ps[16 * 64];
  __shared__ u64 Cs[16 * 64];
  const int tid = threadIdx.x;
  const int i0 = blockIdx.x * 64, j0 = blockIdx.y * 64, ch0 = blockIdx.z * 64;
  const int ti = tid >> 4, tj = tid & 15;
  unsigned cnt[4][4] = {};

  for (int s = 0; s < 4; s++) {
    int cb = ch0 + s * 16;
    #pragma unroll
    for (int r = 0; r < 4; r++) {
      int l = r * 256 + tid;
      int c = l >> 6, f = l & 63;
      Ps[l] = (i0 + f < FP) ? bp[(size_t)(cb + c) * FP + i0 + f] : 0ULL;
      Cs[l] = (j0 + f < FC) ? bc[(size_t)(cb + c) * FC + j0 + f] : 0ULL;
    }
    __syncthreads();
    #pragma unroll 4
    for (int c = 0; c < 16; c++) {
      u64 pv[4], cv[4];
      #pragma unroll
      for (int a = 0; a < 4; a++) pv[a] = Ps[c * 64 + ti * 4 + a];
      #pragma unroll
      for (int b = 0; b < 4; b++) cv[b] = Cs[c * 64 + tj * 4 + b];
      #pragma unroll
      for (int a = 0; a < 4; a++)
        #pragma unroll
        for (int b = 0; b < 4; b++)
          cnt[a][b] += (unsigned)__builtin_popcountll(pv[a] & cv[b]);
    }
    __syncthreads();
  }

  #pragma unroll
  for (int a = 0; a < 4; a++) {
    int i = i0 + ti * 4 + a;
    if (i >= FP) continue;
    #pragma unroll
    for (int b = 0; b < 4; b++) {
      int j = j0 + tj * 4 + b;
      if (j < FC) atomicAdd(&Cm[(size_t)i * FC + j], (float)cnt[a][b]);
    }
  }
}

// ---------- launch ----------
extern "C" void kernel_launch(void* const* d_in, const int* in_sizes, int n_in,
                              void* d_out, int out_size, void* d_ws, size_t ws_size,
                              hipStream_t stream) {
  const float* x  = (const float*)d_in[0];
  const float* W1 = (const float*)d_in[1];
  const float* b1 = (const float*)d_in[2];
  const float* W2 = (const float*)d_in[3];
  const float* b2 = (const float*)d_in[4];
  const float* W3 = (const float*)d_in[5];
  const float* b3 = (const float*)d_in[6];
  const float* W4 = (const float*)d_in[7];
  const float* b4 = (const float*)d_in[8];
  float* out = (float*)d_out;

  constexpr size_t O_C0 = 327680, O_C1 = 528384, O_C2 = 593920, O_C3 = 659456;
  constexpr size_t O_END = 662016;

  char* ws = (char*)d_ws;
  u16* xb   = (u16*)(ws);                 // 32768*800*2 = 52428800
  char* p = ws + 52428800;
  u16* w1b  = (u16*)p;  p += (size_t)256 * 800 * 2;   // 409600
  u16* w2b  = (u16*)p;  p += (size_t)256 * 256 * 2;   // 131072
  u16* w3b  = (u16*)p;  p += (size_t)256 * 256 * 2;   // 131072
  u16* w4b  = (u16*)p;  p += (size_t)16 * 256 * 2;    // 8192
  u64* bits0 = (u64*)p; p += (size_t)512 * 784 * 8;   // 3211264
  u64* bits1 = (u64*)p; p += (size_t)512 * 256 * 8;   // 1048576
  u64* bits2 = (u64*)p; p += (size_t)512 * 256 * 8;
  u64* bits3 = (u64*)p; p += (size_t)512 * 256 * 8;
  u64* bits4 = (u64*)p; p += (size_t)512 * 10 * 8;

  hipMemsetAsync((void*)(out + O_C0), 0, (O_END - O_C0) * sizeof(float), stream);

  convert_pad<<<800, 256, 0, stream>>>(W1, w1b, 256, 784, 256, 800);
  convert_pad<<<256, 256, 0, stream>>>(W2, w2b, 256, 256, 256, 256);
  convert_pad<<<256, 256, 0, stream>>>(W3, w3b, 256, 256, 256, 256);
  convert_pad<<<16, 256, 0, stream>>>(W4, w4b, 10, 256, 16, 256);

  prep_x<<<dim3(13, 512), 256, 0, stream>>>(x, xb, bits0);

  fwd_fused<<<256, 256, 0, stream>>>(xb, w1b, b1, w2b, b2, w3b, b3, w4b, b4,
                                     out, bits1, bits2, bits3, bits4);

  coact<<<dim3(13, 4, 8), 256, 0, stream>>>(bits0, bits1, out + O_C0, 784, 256);
  coact<<<dim3(4, 4, 8), 256, 0, stream>>>(bits1, bits2, out + O_C1, 256, 256);
  coact<<<dim3(4, 4, 8), 256, 0, stream>>>(bits2, bits3, out + O_C2, 256, 256);
  coact<<<dim3(4, 1, 8), 256, 0, stream>>>(bits3, bits4, out + O_C3, 256, 10);
}

// Round 4
// 311.740 us; speedup vs baseline: 1.6431x; 1.1594x over previous
//
#include <hip/hip_runtime.h>
#include <hip/hip_bf16.h>

typedef unsigned short u16;
typedef unsigned long long u64;
typedef __bf16 bf16x8 __attribute__((ext_vector_type(8)));
typedef float f32x4 __attribute__((ext_vector_type(4)));

// ---------- helpers ----------
__device__ __forceinline__ void async16(const void* g, void* l) {
  __builtin_amdgcn_global_load_lds((const __attribute__((address_space(1))) void*)g,
                                   (__attribute__((address_space(3))) void*)l, 16, 0, 0);
}
__device__ __forceinline__ u16 f2bf(float f) {
  __hip_bfloat16 h = __float2bfloat16(f);
  u16 u; __builtin_memcpy(&u, &h, 2); return u;
}

// ---------- fused weight convert + pad (fp32 -> bf16, zero pad) ----------
__global__ __launch_bounds__(256) void convert_all(
    const float* __restrict__ W1, const float* __restrict__ W2,
    const float* __restrict__ W3, const float* __restrict__ W4,
    u16* __restrict__ w1b, u16* __restrict__ w2b,
    u16* __restrict__ w3b, u16* __restrict__ w4b) {
  int bx = blockIdx.x;
  const float* src; u16* dst; int R, C, Cp, base;
  if (bx < 800)       { src = W1; dst = w1b; R = 256; C = 784; Cp = 800; base = 0; }
  else if (bx < 1056) { src = W2; dst = w2b; R = 256; C = 256; Cp = 256; base = 800; }
  else if (bx < 1312) { src = W3; dst = w3b; R = 256; C = 256; Cp = 256; base = 1056; }
  else                { src = W4; dst = w4b; R = 10;  C = 256; Cp = 256; base = 1312; }
  int idx = (bx - base) * 256 + threadIdx.x;
  int r = idx / Cp, c = idx - r * Cp;
  float v = (r < R && c < C) ? src[(size_t)r * C + c] : 0.0f;
  dst[idx] = f2bf(v);
}

// ---------- x: coalesced tile convert fp32[32768][784]->bf16[32768][800] + bits0 ----------
__global__ __launch_bounds__(256) void prep_x(const float* __restrict__ x,
                                              u16* __restrict__ xb,
                                              u64* __restrict__ bits0) {
  __shared__ u16 S[64 * 66];
  const int t = threadIdx.x;
  const int g = blockIdx.x;      // 0..12
  const int chunk = blockIdx.y;  // 0..511
  const int row0 = chunk * 64, col0 = g * 64;

  if (g < 12) {
    #pragma unroll
    for (int i = 0; i < 4; i++) {
      int idx = i * 256 + t;
      int r = idx >> 4, c4 = (idx & 15) * 4;
      float4 v = *(const float4*)(x + (size_t)(row0 + r) * 784 + col0 + c4);
      ushort4 o;
      o.x = f2bf(v.x); o.y = f2bf(v.y); o.z = f2bf(v.z); o.w = f2bf(v.w);
      *(ushort4*)(xb + (size_t)(row0 + r) * 800 + col0 + c4) = o;
      S[r * 66 + c4]     = v.x > 0.0f;
      S[r * 66 + c4 + 1] = v.y > 0.0f;
      S[r * 66 + c4 + 2] = v.z > 0.0f;
      S[r * 66 + c4 + 3] = v.w > 0.0f;
    }
  } else {
    int r = t >> 2, c4 = (t & 3) * 4;
    float4 v = *(const float4*)(x + (size_t)(row0 + r) * 784 + col0 + c4);
    ushort4 o;
    o.x = f2bf(v.x); o.y = f2bf(v.y); o.z = f2bf(v.z); o.w = f2bf(v.w);
    *(ushort4*)(xb + (size_t)(row0 + r) * 800 + col0 + c4) = o;
    ushort4 z = {0, 0, 0, 0};
    *(ushort4*)(xb + (size_t)(row0 + r) * 800 + 784 + c4) = z;
    S[r * 66 + c4]     = v.x > 0.0f;
    S[r * 66 + c4 + 1] = v.y > 0.0f;
    S[r * 66 + c4 + 2] = v.z > 0.0f;
    S[r * 66 + c4 + 3] = v.w > 0.0f;
  }
  __syncthreads();

  const int lane = t & 63, wv = t >> 6;
  const int ncols = (g < 12) ? 64 : 16;
  const int cbase = wv * 16;
  if (cbase < ncols) {
    u64 my = 0;
    #pragma unroll
    for (int i = 0; i < 16; i++) {
      u64 m = __ballot(S[lane * 66 + cbase + i] != 0);
      if (lane == i) my = m;
    }
    if (lane < 16) bits0[(size_t)chunk * 784 + col0 + cbase + lane] = my;
  }
}

// ---------- fully-fused forward: 128 rows/block, 8 waves, h in LDS ----------
__global__ __launch_bounds__(512, 2) void fwd_fused(
    const u16* __restrict__ xb,
    const u16* __restrict__ W1b, const float* __restrict__ b1,
    const u16* __restrict__ W2b, const float* __restrict__ b2,
    const u16* __restrict__ W3b, const float* __restrict__ b3,
    const u16* __restrict__ W4b, const float* __restrict__ b4,
    float* __restrict__ out,
    u16* __restrict__ bits1h, u16* __restrict__ bits2h,
    u16* __restrict__ bits3h, u64* __restrict__ bits4) {

  __shared__ __align__(16) u16 hbuf[8 * 4096];   // h: 8 tiles [kt][128][32] = 64 KB
  __shared__ __align__(16) u16 Wt[2][8192];      // W tile dbuf: 256x32 x2 = 32 KB
  __shared__ __align__(16) u16 At[2][4096];      // A tile dbuf (layer1) = 16 KB

  const int tid = threadIdx.x;
  const int lane = tid & 63, wv = tid >> 6;      // 8 waves
  const int lm = lane & 15, q = lane >> 4;
  const int m0 = blockIdx.x * 128;
  const int wm = (wv & 1) * 64;                  // 0 / 64
  const int wn = (wv >> 1) * 64;                 // 0 / 64 / 128 / 192

  auto stageW = [&](const u16* W, int K, int kc, u16* dst) {
    #pragma unroll
    for (int i = 0; i < 2; i++) {
      int seg = i * 512 + tid;
      int n = seg >> 2, kq = seg & 3;
      async16(W + (size_t)n * K + kc * 32 + kq * 8, dst + seg * 8);
    }
  };
  auto stageA1 = [&](int kc, u16* dst) {
    int r = tid >> 2, kq = tid & 3;
    async16(xb + (size_t)(m0 + r) * 800 + kc * 32 + kq * 8, dst + tid * 8);
  };
  // epilogue: 4x4 frags -> bias+relu -> bf16 -> hbuf
  auto epilogue = [&](f32x4 (&acc)[4][4], const float* __restrict__ bias) {
    #pragma unroll
    for (int ni = 0; ni < 4; ni++) {
      int col = wn + ni * 16 + lm;
      float bv = bias[col];
      int kt = col >> 5, cl = col & 31;
      #pragma unroll
      for (int mi = 0; mi < 4; mi++) {
        #pragma unroll
        for (int r = 0; r < 4; r++) {
          int row = wm + mi * 16 + q * 4 + r;
          float h = acc[mi][ni][r] + bv;
          h = h > 0.0f ? h : 0.0f;
          hbuf[kt * 4096 + row * 32 + cl] = f2bf(h);
        }
      }
    }
  };
  // ballot-from-A-frag: emits 16-bit row pieces of the bit-matrix. rbase = first row of frag.
  auto emit_bits = [&](u16* bitsH, int kc, int rbase, const bf16x8& af) {
    union { bf16x8 v; u16 s[8]; } u; u.v = af;
    int chunk = blockIdx.x * 2 + (rbase >> 6);
    int slot = (rbase & 63) >> 4;
    #pragma unroll
    for (int j = 0; j < 8; j++) {
      u64 m = __ballot(u.s[j] != 0);
      if (lm == j) {
        int col = kc * 32 + q * 8 + j;
        bitsH[((size_t)chunk * 256 + col) * 4 + slot] = (u16)(m >> (q * 16));
      }
    }
  };

  // ---- layer 1: K=800, A from xb ----
  {
    f32x4 acc[4][4] = {};
    stageA1(0, At[0]);
    stageW(W1b, 800, 0, Wt[0]);
    for (int kc = 0; kc < 25; kc++) {
      int cur = kc & 1;
      __syncthreads();
      if (kc < 24) { stageA1(kc + 1, At[1 - cur]); stageW(W1b, 800, kc + 1, Wt[1 - cur]); }
      else         { stageW(W2b, 256, 0, Wt[1]); }      // cur=0 at kc=24
      const bf16x8* Av = (const bf16x8*)At[cur];
      const bf16x8* Bv = (const bf16x8*)Wt[cur];
      bf16x8 a[4], b[4];
      #pragma unroll
      for (int mi = 0; mi < 4; mi++) a[mi] = Av[(wm + mi * 16 + lm) * 4 + q];
      #pragma unroll
      for (int ni = 0; ni < 4; ni++) b[ni] = Bv[(wn + ni * 16 + lm) * 4 + q];
      #pragma unroll
      for (int mi = 0; mi < 4; mi++)
        #pragma unroll
        for (int ni = 0; ni < 4; ni++)
          acc[mi][ni] = __builtin_amdgcn_mfma_f32_16x16x32_bf16(a[mi], b[ni], acc[mi][ni], 0, 0, 0);
    }
    epilogue(acc, b1);
  }

  // ---- layers 2,3: K=256, A from hbuf; emits bits of PREVIOUS h from a-frags ----
  // layer2: W2 kc0 pre-staged in Wt[1]; prefetches W3 kc0 at the end.
  {
    f32x4 acc[4][4] = {};
    for (int kc = 0; kc < 8; kc++) {
      int cur = (kc & 1) ^ 1;
      __syncthreads();
      if (kc < 7) stageW(W2b, 256, kc + 1, Wt[cur ^ 1]);
      else        stageW(W3b, 256, 0, Wt[cur ^ 1]);     // cur=0 at kc=7 -> Wt[1]
      const bf16x8* Hv = (const bf16x8*)(hbuf + kc * 4096);
      const bf16x8* Bv = (const bf16x8*)Wt[cur];
      bf16x8 a[4], b[4];
      #pragma unroll
      for (int mi = 0; mi < 4; mi++) a[mi] = Hv[(wm + mi * 16 + lm) * 4 + q];
      #pragma unroll
      for (int ni = 0; ni < 4; ni++) b[ni] = Bv[(wn + ni * 16 + lm) * 4 + q];
      emit_bits(bits1h, kc, wm + (wv >> 1) * 16, a[wv >> 1]);   // each wave emits one mi
      #pragma unroll
      for (int mi = 0; mi < 4; mi++)
        #pragma unroll
        for (int ni = 0; ni < 4; ni++)
          acc[mi][ni] = __builtin_amdgcn_mfma_f32_16x16x32_bf16(a[mi], b[ni], acc[mi][ni], 0, 0, 0);
    }
    __syncthreads();   // hbuf reads done before overwrite
    epilogue(acc, b2);
  }
  {
    f32x4 acc[4][4] = {};
    for (int kc = 0; kc < 8; kc++) {
      int cur = (kc & 1) ^ 1;
      __syncthreads();
      if (kc < 7) stageW(W3b, 256, kc + 1, Wt[cur ^ 1]);
      else        { if (tid < 512) async16(W4b + tid * 8, Wt[1] + tid * 8); }  // W4 8KB -> Wt[1]
      const bf16x8* Hv = (const bf16x8*)(hbuf + kc * 4096);
      const bf16x8* Bv = (const bf16x8*)Wt[cur];
      bf16x8 a[4], b[4];
      #pragma unroll
      for (int mi = 0; mi < 4; mi++) a[mi] = Hv[(wm + mi * 16 + lm) * 4 + q];
      #pragma unroll
      for (int ni = 0; ni < 4; ni++) b[ni] = Bv[(wn + ni * 16 + lm) * 4 + q];
      emit_bits(bits2h, kc, wm + (wv >> 1) * 16, a[wv >> 1]);
      #pragma unroll
      for (int mi = 0; mi < 4; mi++)
        #pragma unroll
        for (int ni = 0; ni < 4; ni++)
          acc[mi][ni] = __builtin_amdgcn_mfma_f32_16x16x32_bf16(a[mi], b[ni], acc[mi][ni], 0, 0, 0);
    }
    __syncthreads();
    epilogue(acc, b3);
  }

  // ---- logits: each wave 16 rows; K=256, N=16 (padded); emits bits3 ----
  {
    __syncthreads();   // h3 visible; W4 staged (drained by this barrier)
    const int r0 = wv * 16;
    const bf16x8* Bv = (const bf16x8*)Wt[1];
    f32x4 acc = {};
    #pragma unroll
    for (int kc = 0; kc < 8; kc++) {
      bf16x8 a = ((const bf16x8*)(hbuf + kc * 4096))[(r0 + lm) * 4 + q];
      bf16x8 b = Bv[lm * 32 + kc * 4 + q];
      emit_bits(bits3h, kc, r0, a);
      acc = __builtin_amdgcn_mfma_f32_16x16x32_bf16(a, b, acc, 0, 0, 0);
    }
    float* Ls = (float*)At;                        // 128 x 17 fp32 (conflict-free)
    float bv = (lm < 10) ? b4[lm] : 0.0f;
    #pragma unroll
    for (int r = 0; r < 4; r++) {
      int row = r0 + q * 4 + r;
      float v = acc[r] + bv;
      Ls[row * 17 + lm] = v;
      if (lm < 10) out[(size_t)(m0 + row) * 10 + lm] = v;
    }
    __syncthreads();
    if (wv < 2) {
      int row = wv * 64 + lane;
      u64 my = 0;
      #pragma unroll
      for (int c = 0; c < 10; c++) {
        u64 m = __ballot(Ls[row * 17 + c] > 0.0f);
        if (lane == c) my = m;
      }
      if (lane < 10) bits4[(size_t)(blockIdx.x * 2 + wv) * 10 + lane] = my;
    }
  }
}

// ---------- fused coactivations: grid (88, 8) ----------
__global__ __launch_bounds__(256) void coact_all(
    const u64* __restrict__ bits0, const u64* __restrict__ bits1,
    const u64* __restrict__ bits2, const u64* __restrict__ bits3,
    const u64* __restrict__ bits4, float* __restrict__ out) {
  const int bx = blockIdx.x;
  const u64 *bp, *bc; float* Cm; int FP, FC, i0, j0;
  if (bx < 52)      { bp = bits0; bc = bits1; Cm = out + 327680; FP = 784; FC = 256;
                      i0 = (bx % 13) * 64; j0 = (bx / 13) * 64; }
  else if (bx < 68) { int t = bx - 52; bp = bits1; bc = bits2; Cm = out + 528384; FP = 256; FC = 256;
                      i0 = (t & 3) * 64; j0 = (t >> 2) * 64; }
  else if (bx < 84) { int t = bx - 68; bp = bits2; bc = bits3; Cm = out + 593920; FP = 256; FC = 256;
                      i0 = (t & 3) * 64; j0 = (t >> 2) * 64; }
  else              { int t = bx - 84; bp = bits3; bc = bits4; Cm = out + 659456; FP = 256; FC = 10;
                      i0 = t * 64; j0 = 0; }

  __shared__ u64 Ps[16 * 64];
  __shared__ u64 Cs[16 * 64];
  const int tid = threadIdx.x;
  const int ch0 = blockIdx.y * 64;
  const int ti = tid >> 4, tj = tid & 15;
  unsigned cnt[4][4] = {};

  for (int s = 0; s < 4; s++) {
    int cb = ch0 + s * 16;
    #pragma unroll
    for (int r = 0; r < 4; r++) {
      int l = r * 256 + tid;
      int c = l >> 6, f = l & 63;
      Ps[l] = (i0 + f < FP) ? bp[(size_t)(cb + c) * FP + i0 + f] : 0ULL;
      Cs[l] = (j0 + f < FC) ? bc[(size_t)(cb + c) * FC + j0 + f] : 0ULL;
    }
    __syncthreads();
    #pragma unroll 4
    for (int c = 0; c < 16; c++) {
      u64 pv[4], cv[4];
      #pragma unroll
      for (int a = 0; a < 4; a++) pv[a] = Ps[c * 64 + ti * 4 + a];
      #pragma unroll
      for (int b = 0; b < 4; b++) cv[b] = Cs[c * 64 + tj * 4 + b];
      #pragma unroll
      for (int a = 0; a < 4; a++)
        #pragma unroll
        for (int b = 0; b < 4; b++)
          cnt[a][b] += (unsigned)__builtin_popcountll(pv[a] & cv[b]);
    }
    __syncthreads();
  }

  #pragma unroll
  for (int a = 0; a < 4; a++) {
    int i = i0 + ti * 4 + a;
    if (i >= FP) continue;
    #pragma unroll
    for (int b = 0; b < 4; b++) {
      int j = j0 + tj * 4 + b;
      if (j < FC) atomicAdd(&Cm[(size_t)i * FC + j], (float)cnt[a][b]);
    }
  }
}

// ---------- launch ----------
extern "C" void kernel_launch(void* const* d_in, const int* in_sizes, int n_in,
                              void* d_out, int out_size, void* d_ws, size_t ws_size,
                              hipStream_t stream) {
  const float* x  = (const float*)d_in[0];
  const float* W1 = (const float*)d_in[1];
  const float* b1 = (const float*)d_in[2];
  const float* W2 = (const float*)d_in[3];
  const float* b2 = (const float*)d_in[4];
  const float* W3 = (const float*)d_in[5];
  const float* b3 = (const float*)d_in[6];
  const float* W4 = (const float*)d_in[7];
  const float* b4 = (const float*)d_in[8];
  float* out = (float*)d_out;

  constexpr size_t O_C0 = 327680, O_END = 662016;

  char* ws = (char*)d_ws;
  u16* xb   = (u16*)(ws);                 // 32768*800*2 = 52428800
  char* p = ws + 52428800;
  u16* w1b  = (u16*)p;  p += (size_t)256 * 800 * 2;
  u16* w2b  = (u16*)p;  p += (size_t)256 * 256 * 2;
  u16* w3b  = (u16*)p;  p += (size_t)256 * 256 * 2;
  u16* w4b  = (u16*)p;  p += (size_t)16 * 256 * 2;
  u64* bits0 = (u64*)p; p += (size_t)512 * 784 * 8;
  u64* bits1 = (u64*)p; p += (size_t)512 * 256 * 8;
  u64* bits2 = (u64*)p; p += (size_t)512 * 256 * 8;
  u64* bits3 = (u64*)p; p += (size_t)512 * 256 * 8;
  u64* bits4 = (u64*)p; p += (size_t)512 * 10 * 8;

  hipMemsetAsync((void*)(out + O_C0), 0, (O_END - O_C0) * sizeof(float), stream);

  convert_all<<<1328, 256, 0, stream>>>(W1, W2, W3, W4, w1b, w2b, w3b, w4b);
  prep_x<<<dim3(13, 512), 256, 0, stream>>>(x, xb, bits0);

  fwd_fused<<<256, 512, 0, stream>>>(xb, w1b, b1, w2b, b2, w3b, b3, w4b, b4,
                                     out, (u16*)bits1, (u16*)bits2, (u16*)bits3, bits4);

  coact_all<<<dim3(88, 8), 256, 0, stream>>>(bits0, bits1, bits2, bits3, bits4, out);
}

// Round 6
// 271.501 us; speedup vs baseline: 1.8866x; 1.1482x over previous
//
#include <hip/hip_runtime.h>
#include <hip/hip_bf16.h>

typedef unsigned short u16;
typedef unsigned long long u64;
typedef __bf16 bf16x8 __attribute__((ext_vector_type(8)));
typedef float f32x4 __attribute__((ext_vector_type(4)));

// ---------- helpers ----------
__device__ __forceinline__ void async16(const void* g, void* l) {
  __builtin_amdgcn_global_load_lds((const __attribute__((address_space(1))) void*)g,
                                   (__attribute__((address_space(3))) void*)l, 16, 0, 0);
}
__device__ __forceinline__ u16 f2bf(float f) {
  __hip_bfloat16 h = __float2bfloat16(f);
  u16 u; __builtin_memcpy(&u, &h, 2); return u;
}

// ---------- fused weight convert + pad (fp32 -> bf16, zero pad) ----------
__global__ __launch_bounds__(256) void convert_all(
    const float* __restrict__ W1, const float* __restrict__ W2,
    const float* __restrict__ W3, const float* __restrict__ W4,
    u16* __restrict__ w1b, u16* __restrict__ w2b,
    u16* __restrict__ w3b, u16* __restrict__ w4b) {
  int bx = blockIdx.x;
  const float* src; u16* dst; int R, C, Cp, base;
  if (bx < 800)       { src = W1; dst = w1b; R = 256; C = 784; Cp = 800; base = 0; }
  else if (bx < 1056) { src = W2; dst = w2b; R = 256; C = 256; Cp = 256; base = 800; }
  else if (bx < 1312) { src = W3; dst = w3b; R = 256; C = 256; Cp = 256; base = 1056; }
  else                { src = W4; dst = w4b; R = 10;  C = 256; Cp = 256; base = 1312; }
  int idx = (bx - base) * 256 + threadIdx.x;
  int r = idx / Cp, c = idx - r * Cp;
  float v = (r < R && c < C) ? src[(size_t)r * C + c] : 0.0f;
  dst[idx] = f2bf(v);
}

// ---------- x: coalesced tile convert fp32[32768][784]->bf16[32768][800] + bits0 ----------
__global__ __launch_bounds__(256) void prep_x(const float* __restrict__ x,
                                              u16* __restrict__ xb,
                                              u64* __restrict__ bits0) {
  __shared__ u16 S[64 * 66];
  const int t = threadIdx.x;
  const int g = blockIdx.x;      // 0..12
  const int chunk = blockIdx.y;  // 0..511
  const int row0 = chunk * 64, col0 = g * 64;

  if (g < 12) {
    #pragma unroll
    for (int i = 0; i < 4; i++) {
      int idx = i * 256 + t;
      int r = idx >> 4, c4 = (idx & 15) * 4;
      float4 v = *(const float4*)(x + (size_t)(row0 + r) * 784 + col0 + c4);
      ushort4 o;
      o.x = f2bf(v.x); o.y = f2bf(v.y); o.z = f2bf(v.z); o.w = f2bf(v.w);
      *(ushort4*)(xb + (size_t)(row0 + r) * 800 + col0 + c4) = o;
      S[r * 66 + c4]     = v.x > 0.0f;
      S[r * 66 + c4 + 1] = v.y > 0.0f;
      S[r * 66 + c4 + 2] = v.z > 0.0f;
      S[r * 66 + c4 + 3] = v.w > 0.0f;
    }
  } else {
    int r = t >> 2, c4 = (t & 3) * 4;
    float4 v = *(const float4*)(x + (size_t)(row0 + r) * 784 + col0 + c4);
    ushort4 o;
    o.x = f2bf(v.x); o.y = f2bf(v.y); o.z = f2bf(v.z); o.w = f2bf(v.w);
    *(ushort4*)(xb + (size_t)(row0 + r) * 800 + col0 + c4) = o;
    ushort4 z = {0, 0, 0, 0};
    *(ushort4*)(xb + (size_t)(row0 + r) * 800 + 784 + c4) = z;
    S[r * 66 + c4]     = v.x > 0.0f;
    S[r * 66 + c4 + 1] = v.y > 0.0f;
    S[r * 66 + c4 + 2] = v.z > 0.0f;
    S[r * 66 + c4 + 3] = v.w > 0.0f;
  }
  __syncthreads();

  const int lane = t & 63, wv = t >> 6;
  const int ncols = (g < 12) ? 64 : 16;
  const int cbase = wv * 16;
  if (cbase < ncols) {
    u64 my = 0;
    #pragma unroll
    for (int i = 0; i < 16; i++) {
      u64 m = __ballot(S[lane * 66 + cbase + i] != 0);
      if (lane == i) my = m;
    }
    if (lane < 16) bits0[(size_t)chunk * 784 + col0 + cbase + lane] = my;
  }
}

// ---------- fully-fused forward: 64 rows/block, 8 waves, 2 blocks/CU ----------
// hbuf rows padded to 40 u16 (80 B): frag reads balanced-8 (b128 min),
// epilogue b64 writes balanced-4 (b64 min), 16 B-aligned for staging.
// NOTE: global_load_lds dest = wave-uniform base + lane*16 (m104/m108) —
// every async16 call keeps per-lane LDS offsets == lane-contiguous*16B.
__global__ __launch_bounds__(512, 4) void fwd_fused(
    const u16* __restrict__ xb,
    const u16* __restrict__ W1b, const float* __restrict__ b1,
    const u16* __restrict__ W2b, const float* __restrict__ b2,
    const u16* __restrict__ W3b, const float* __restrict__ b3,
    const u16* __restrict__ W4b, const float* __restrict__ b4,
    float* __restrict__ out,
    u64* __restrict__ bits1, u64* __restrict__ bits2,
    u64* __restrict__ bits3, u64* __restrict__ bits4) {

  __shared__ __align__(16) u16 hbuf[8 * 64 * 40];  // 40 KB: 8 kt-tiles [64 rows][32+8 pad]
  __shared__ __align__(16) u16 Wt[2][256 * 32];    // 32 KB: W tile dbuf
  __shared__ __align__(16) u16 At[2][64 * 32];     // 8 KB: x tile dbuf (layer1); Ls scratch later

  const int tid = threadIdx.x;
  const int lane = tid & 63, wv = tid >> 6;        // 8 waves
  const int lm = lane & 15, q = lane >> 4;
  const int m0 = blockIdx.x * 64;
  const int wm = (wv & 1) * 32;                    // rows 0/32
  const int wn = (wv >> 1) * 64;                   // cols 0/64/128/192

  auto stageW = [&](const u16* W, int K, int kc, u16* dst) {
    #pragma unroll
    for (int i = 0; i < 2; i++) {
      int seg = i * 512 + tid;
      int n = seg >> 2, kq = seg & 3;
      async16(W + (size_t)n * K + kc * 32 + kq * 8, dst + seg * 8);
    }
  };
  auto stageA = [&](int kc, u16* dst) {
    if (tid < 256) {
      int r = tid >> 2, kq = tid & 3;
      async16(xb + (size_t)(m0 + r) * 800 + kc * 32 + kq * 8, dst + tid * 8);
    }
  };
  auto stageW4 = [&]() {   // W4b [16][256] -> Wt[1] CONTIGUOUS (lane-linear dest!)
    if (tid < 512) async16(W4b + tid * 8, Wt[1] + tid * 8);
  };
  // operand-swapped epilogue: lane (lm,q) holds rows wm+mi*16+lm, cols wn+ni*16+q*4..+3
  auto epilogue = [&](f32x4 (&acc)[2][4], const float* __restrict__ bias) {
    #pragma unroll
    for (int mi = 0; mi < 2; mi++) {
      int row = wm + mi * 16 + lm;
      #pragma unroll
      for (int ni = 0; ni < 4; ni++) {
        int col = wn + ni * 16 + q * 4;
        float4 bv = *(const float4*)(bias + col);
        float h0 = acc[mi][ni][0] + bv.x; h0 = h0 > 0.0f ? h0 : 0.0f;
        float h1 = acc[mi][ni][1] + bv.y; h1 = h1 > 0.0f ? h1 : 0.0f;
        float h2 = acc[mi][ni][2] + bv.z; h2 = h2 > 0.0f ? h2 : 0.0f;
        float h3 = acc[mi][ni][3] + bv.w; h3 = h3 > 0.0f ? h3 : 0.0f;
        ushort4 o = {f2bf(h0), f2bf(h1), f2bf(h2), f2bf(h3)};
        int kt = col >> 5, cin = col & 31;
        *(ushort4*)(hbuf + kt * 2560 + row * 40 + cin) = o;
      }
    }
  };
  // conflict-free bitpack: wave wv handles kt=wv; lane = row (64 rows = this block's chunk)
  auto ballot_pass = [&](u64* bits) {
    u64 my = 0;
    #pragma unroll
    for (int g = 0; g < 4; g++) {
      ushort4 v0 = *(const ushort4*)(hbuf + wv * 2560 + lane * 40 + g * 8);
      ushort4 v1 = *(const ushort4*)(hbuf + wv * 2560 + lane * 40 + g * 8 + 4);
      u16 s[8] = {v0.x, v0.y, v0.z, v0.w, v1.x, v1.y, v1.z, v1.w};
      #pragma unroll
      for (int j = 0; j < 8; j++) {
        u64 m = __ballot(s[j] != 0);
        if (lane == g * 8 + j) my = m;
      }
    }
    if (lane < 32) bits[(size_t)blockIdx.x * 256 + wv * 32 + lane] = my;
  };

  // ---- layer 1: K=800 ----
  {
    f32x4 acc[2][4] = {};
    stageA(0, At[0]);
    stageW(W1b, 800, 0, Wt[0]);
    for (int kc = 0; kc < 25; kc++) {
      int cur = kc & 1;
      __syncthreads();   // drains this kc's staging (issued one full compute phase ago)
      if (kc < 24) { stageA(kc + 1, At[1 - cur]); stageW(W1b, 800, kc + 1, Wt[1 - cur]); }
      else         { stageW(W2b, 256, 0, Wt[1]); }          // cur=0 at kc=24
      bf16x8 w[4], h[2];
      #pragma unroll
      for (int ni = 0; ni < 4; ni++) w[ni] = *(const bf16x8*)(Wt[cur] + (wn + ni * 16 + lm) * 32 + q * 8);
      #pragma unroll
      for (int mi = 0; mi < 2; mi++) h[mi] = *(const bf16x8*)(At[cur] + (wm + mi * 16 + lm) * 32 + q * 8);
      #pragma unroll
      for (int mi = 0; mi < 2; mi++)
        #pragma unroll
        for (int ni = 0; ni < 4; ni++)
          acc[mi][ni] = __builtin_amdgcn_mfma_f32_16x16x32_bf16(w[ni], h[mi], acc[mi][ni], 0, 0, 0);
    }
    __syncthreads();
    epilogue(acc, b1);
  }
  __syncthreads();
  ballot_pass(bits1);

  // ---- layers 2,3: K=256, A from hbuf ----
  auto layer256 = [&](const u16* Wthis, const u16* Wnext, bool nextIsW4,
                      const float* __restrict__ bias, u64* bits) {
    f32x4 acc[2][4] = {};
    for (int kc = 0; kc < 8; kc++) {
      int cur = (kc & 1) ^ 1;
      __syncthreads();
      if (kc < 7)       stageW(Wthis, 256, kc + 1, Wt[cur ^ 1]);
      else if (nextIsW4) stageW4();                          // cur=0 at kc=7 -> Wt[1]
      else              stageW(Wnext, 256, 0, Wt[cur ^ 1]);
      bf16x8 w[4], h[2];
      #pragma unroll
      for (int ni = 0; ni < 4; ni++) w[ni] = *(const bf16x8*)(Wt[cur] + (wn + ni * 16 + lm) * 32 + q * 8);
      #pragma unroll
      for (int mi = 0; mi < 2; mi++) h[mi] = *(const bf16x8*)(hbuf + kc * 2560 + (wm + mi * 16 + lm) * 40 + q * 8);
      #pragma unroll
      for (int mi = 0; mi < 2; mi++)
        #pragma unroll
        for (int ni = 0; ni < 4; ni++)
          acc[mi][ni] = __builtin_amdgcn_mfma_f32_16x16x32_bf16(w[ni], h[mi], acc[mi][ni], 0, 0, 0);
    }
    __syncthreads();     // all hbuf reads complete before overwrite
    epilogue(acc, bias);
    __syncthreads();
    ballot_pass(bits);
  };
  layer256(W2b, W3b, false, b2, bits2);
  layer256(W3b, W4b, true,  b3, bits3);

  // ---- logits: waves 0..3, 16 rows each; W4 in Wt[1] contiguous [16][256] ----
  if (wv < 4) {
    const int r0 = wv * 16;
    f32x4 acc = {};
    #pragma unroll
    for (int kc = 0; kc < 8; kc++) {
      bf16x8 wf = *(const bf16x8*)(Wt[1] + lm * 256 + kc * 32 + q * 8);
      bf16x8 hf = *(const bf16x8*)(hbuf + kc * 2560 + (r0 + lm) * 40 + q * 8);
      acc = __builtin_amdgcn_mfma_f32_16x16x32_bf16(wf, hf, acc, 0, 0, 0);
    }
    // lane (lm,q): row = r0+lm, classes q*4..q*4+3
    int row = r0 + lm;
    float4 v;
    #pragma unroll
    for (int r = 0; r < 4; r++) {
      int c = q * 4 + r;
      float bv = (c < 10) ? b4[c] : 0.0f;
      v[r] = acc[r] + bv;
    }
    float* Ls = (float*)At;                    // [64][12] fp32
    if (q < 3) *(float4*)(Ls + row * 12 + q * 4) = v;
    size_t ob = (size_t)(m0 + row) * 10;
    if (q < 2) {
      *(float2*)(out + ob + q * 4)     = make_float2(v[0], v[1]);
      *(float2*)(out + ob + q * 4 + 2) = make_float2(v[2], v[3]);
    } else if (q == 2) {
      *(float2*)(out + ob + 8) = make_float2(v[0], v[1]);
    }
  }
  __syncthreads();
  if (wv == 0) {
    const float* Ls = (const float*)At;
    float4 c03 = *(const float4*)(Ls + lane * 12);
    float4 c47 = *(const float4*)(Ls + lane * 12 + 4);
    float2 c89 = *(const float2*)(Ls + lane * 12 + 8);
    float s[10] = {c03.x, c03.y, c03.z, c03.w, c47.x, c47.y, c47.z, c47.w, c89.x, c89.y};
    u64 my = 0;
    #pragma unroll
    for (int c = 0; c < 10; c++) {
      u64 m = __ballot(s[c] > 0.0f);
      if (lane == c) my = m;
    }
    if (lane < 10) bits4[(size_t)blockIdx.x * 10 + lane] = my;
  }
}

// ---------- fused coactivations: grid (88, 8) ----------
__global__ __launch_bounds__(256) void coact_all(
    const u64* __restrict__ bits0, const u64* __restrict__ bits1,
    const u64* __restrict__ bits2, const u64* __restrict__ bits3,
    const u64* __restrict__ bits4, float* __restrict__ out) {
  const int bx = blockIdx.x;
  const u64 *bp, *bc; float* Cm; int FP, FC, i0, j0;
  if (bx < 52)      { bp = bits0; bc = bits1; Cm = out + 327680; FP = 784; FC = 256;
                      i0 = (bx % 13) * 64; j0 = (bx / 13) * 64; }
  else if (bx < 68) { int t = bx - 52; bp = bits1; bc = bits2; Cm = out + 528384; FP = 256; FC = 256;
                      i0 = (t & 3) * 64; j0 = (t >> 2) * 64; }
  else if (bx < 84) { int t = bx - 68; bp = bits2; bc = bits3; Cm = out + 593920; FP = 256; FC = 256;
                      i0 = (t & 3) * 64; j0 = (t >> 2) * 64; }
  else              { int t = bx - 84; bp = bits3; bc = bits4; Cm = out + 659456; FP = 256; FC = 10;
                      i0 = t * 64; j0 = 0; }

  __shared__ u64 Ps[16 * 64];
  __shared__ u64 Cs[16 * 64];
  const int tid = threadIdx.x;
  const int ch0 = blockIdx.y * 64;
  const int ti = tid >> 4, tj = tid & 15;
  unsigned cnt[4][4] = {};

  for (int s = 0; s < 4; s++) {
    int cb = ch0 + s * 16;
    #pragma unroll
    for (int r = 0; r < 4; r++) {
      int l = r * 256 + tid;
      int c = l >> 6, f = l & 63;
      Ps[l] = (i0 + f < FP) ? bp[(size_t)(cb + c) * FP + i0 + f] : 0ULL;
      Cs[l] = (j0 + f < FC) ? bc[(size_t)(cb + c) * FC + j0 + f] : 0ULL;
    }
    __syncthreads();
    #pragma unroll 4
    for (int c = 0; c < 16; c++) {
      u64 pv[4], cv[4];
      #pragma unroll
      for (int a = 0; a < 4; a++) pv[a] = Ps[c * 64 + ti * 4 + a];
      #pragma unroll
      for (int b = 0; b < 4; b++) cv[b] = Cs[c * 64 + tj * 4 + b];
      #pragma unroll
      for (int a = 0; a < 4; a++)
        #pragma unroll
        for (int b = 0; b < 4; b++)
          cnt[a][b] += (unsigned)__builtin_popcountll(pv[a] & cv[b]);
    }
    __syncthreads();
  }

  #pragma unroll
  for (int a = 0; a < 4; a++) {
    int i = i0 + ti * 4 + a;
    if (i >= FP) continue;
    #pragma unroll
    for (int b = 0; b < 4; b++) {
      int j = j0 + tj * 4 + b;
      if (j < FC) atomicAdd(&Cm[(size_t)i * FC + j], (float)cnt[a][b]);
    }
  }
}

// ---------- launch ----------
extern "C" void kernel_launch(void* const* d_in, const int* in_sizes, int n_in,
                              void* d_out, int out_size, void* d_ws, size_t ws_size,
                              hipStream_t stream) {
  const float* x  = (const float*)d_in[0];
  const float* W1 = (const float*)d_in[1];
  const float* b1 = (const float*)d_in[2];
  const float* W2 = (const float*)d_in[3];
  const float* b2 = (const float*)d_in[4];
  const float* W3 = (const float*)d_in[5];
  const float* b3 = (const float*)d_in[6];
  const float* W4 = (const float*)d_in[7];
  const float* b4 = (const float*)d_in[8];
  float* out = (float*)d_out;

  constexpr size_t O_C0 = 327680, O_END = 662016;

  char* ws = (char*)d_ws;
  u16* xb   = (u16*)(ws);                 // 32768*800*2 = 52428800
  char* p = ws + 52428800;
  u16* w1b  = (u16*)p;  p += (size_t)256 * 800 * 2;
  u16* w2b  = (u16*)p;  p += (size_t)256 * 256 * 2;
  u16* w3b  = (u16*)p;  p += (size_t)256 * 256 * 2;
  u16* w4b  = (u16*)p;  p += (size_t)16 * 256 * 2;
  u64* bits0 = (u64*)p; p += (size_t)512 * 784 * 8;
  u64* bits1 = (u64*)p; p += (size_t)512 * 256 * 8;
  u64* bits2 = (u64*)p; p += (size_t)512 * 256 * 8;
  u64* bits3 = (u64*)p; p += (size_t)512 * 256 * 8;
  u64* bits4 = (u64*)p; p += (size_t)512 * 10 * 8;

  hipMemsetAsync((void*)(out + O_C0), 0, (O_END - O_C0) * sizeof(float), stream);

  convert_all<<<1328, 256, 0, stream>>>(W1, W2, W3, W4, w1b, w2b, w3b, w4b);
  prep_x<<<dim3(13, 512), 256, 0, stream>>>(x, xb, bits0);

  fwd_fused<<<512, 512, 0, stream>>>(xb, w1b, b1, w2b, b2, w3b, b3, w4b, b4,
                                     out, bits1, bits2, bits3, bits4);

  coact_all<<<dim3(88, 8), 256, 0, stream>>>(bits0, bits1, bits2, bits3, bits4, out);
}

// Round 7
// 247.576 us; speedup vs baseline: 2.0689x; 1.0966x over previous
//
#include <hip/hip_runtime.h>
#include <hip/hip_bf16.h>

typedef unsigned short u16;
typedef unsigned long long u64;
typedef __bf16 bf16x8 __attribute__((ext_vector_type(8)));
typedef float f32x4 __attribute__((ext_vector_type(4)));

// ---------- helpers ----------
__device__ __forceinline__ void async16(const void* g, void* l) {
  __builtin_amdgcn_global_load_lds((const __attribute__((address_space(1))) void*)g,
                                   (__attribute__((address_space(3))) void*)l, 16, 0, 0);
}
__device__ __forceinline__ u16 f2bf(float f) {
  __hip_bfloat16 h = __float2bfloat16(f);
  u16 u; __builtin_memcpy(&u, &h, 2); return u;
}

// ---------- fused weight convert + pad (fp32 -> bf16, zero pad) ----------
__global__ __launch_bounds__(256) void convert_all(
    const float* __restrict__ W1, const float* __restrict__ W2,
    const float* __restrict__ W3, const float* __restrict__ W4,
    u16* __restrict__ w1b, u16* __restrict__ w2b,
    u16* __restrict__ w3b, u16* __restrict__ w4b) {
  int bx = blockIdx.x;
  const float* src; u16* dst; int R, C, Cp, base;
  if (bx < 800)       { src = W1; dst = w1b; R = 256; C = 784; Cp = 800; base = 0; }
  else if (bx < 1056) { src = W2; dst = w2b; R = 256; C = 256; Cp = 256; base = 800; }
  else if (bx < 1312) { src = W3; dst = w3b; R = 256; C = 256; Cp = 256; base = 1056; }
  else                { src = W4; dst = w4b; R = 10;  C = 256; Cp = 256; base = 1312; }
  int idx = (bx - base) * 256 + threadIdx.x;
  int r = idx / Cp, c = idx - r * Cp;
  float v = (r < R && c < C) ? src[(size_t)r * C + c] : 0.0f;
  dst[idx] = f2bf(v);
}

// ---------- x: coalesced tile convert fp32[32768][784]->bf16[32768][800] + bits0 ----------
__global__ __launch_bounds__(256) void prep_x(const float* __restrict__ x,
                                              u16* __restrict__ xb,
                                              u64* __restrict__ bits0) {
  __shared__ u16 S[64 * 66];
  const int t = threadIdx.x;
  const int g = blockIdx.x;      // 0..12
  const int chunk = blockIdx.y;  // 0..511
  const int row0 = chunk * 64, col0 = g * 64;

  if (g < 12) {
    #pragma unroll
    for (int i = 0; i < 4; i++) {
      int idx = i * 256 + t;
      int r = idx >> 4, c4 = (idx & 15) * 4;
      float4 v = *(const float4*)(x + (size_t)(row0 + r) * 784 + col0 + c4);
      ushort4 o;
      o.x = f2bf(v.x); o.y = f2bf(v.y); o.z = f2bf(v.z); o.w = f2bf(v.w);
      *(ushort4*)(xb + (size_t)(row0 + r) * 800 + col0 + c4) = o;
      S[r * 66 + c4]     = v.x > 0.0f;
      S[r * 66 + c4 + 1] = v.y > 0.0f;
      S[r * 66 + c4 + 2] = v.z > 0.0f;
      S[r * 66 + c4 + 3] = v.w > 0.0f;
    }
  } else {
    int r = t >> 2, c4 = (t & 3) * 4;
    float4 v = *(const float4*)(x + (size_t)(row0 + r) * 784 + col0 + c4);
    ushort4 o;
    o.x = f2bf(v.x); o.y = f2bf(v.y); o.z = f2bf(v.z); o.w = f2bf(v.w);
    *(ushort4*)(xb + (size_t)(row0 + r) * 800 + col0 + c4) = o;
    ushort4 z = {0, 0, 0, 0};
    *(ushort4*)(xb + (size_t)(row0 + r) * 800 + 784 + c4) = z;
    S[r * 66 + c4]     = v.x > 0.0f;
    S[r * 66 + c4 + 1] = v.y > 0.0f;
    S[r * 66 + c4 + 2] = v.z > 0.0f;
    S[r * 66 + c4 + 3] = v.w > 0.0f;
  }
  __syncthreads();

  const int lane = t & 63, wv = t >> 6;
  const int ncols = (g < 12) ? 64 : 16;
  const int cbase = wv * 16;
  if (cbase < ncols) {
    u64 my = 0;
    #pragma unroll
    for (int i = 0; i < 16; i++) {
      u64 m = __ballot(S[lane * 66 + cbase + i] != 0);
      if (lane == i) my = m;
    }
    if (lane < 16) bits0[(size_t)chunk * 784 + col0 + cbase + lane] = my;
  }
}

// ---------- fully-fused forward: 64 rows/block, 8 waves, 2 blocks/CU ----------
__global__ __launch_bounds__(512, 4) void fwd_fused(
    const u16* __restrict__ xb,
    const u16* __restrict__ W1b, const float* __restrict__ b1,
    const u16* __restrict__ W2b, const float* __restrict__ b2,
    const u16* __restrict__ W3b, const float* __restrict__ b3,
    const u16* __restrict__ W4b, const float* __restrict__ b4,
    float* __restrict__ out,
    u64* __restrict__ bits1, u64* __restrict__ bits2,
    u64* __restrict__ bits3, u64* __restrict__ bits4) {

  __shared__ __align__(16) u16 hbuf[8 * 64 * 40];  // 40 KB: 8 kt-tiles [64 rows][32+8 pad]
  __shared__ __align__(16) u16 Wt[2][256 * 32];    // 32 KB: W tile dbuf
  __shared__ __align__(16) u16 At[2][64 * 32];     // 8 KB: x tile dbuf (layer1); Ls scratch later

  const int tid = threadIdx.x;
  const int lane = tid & 63, wv = tid >> 6;        // 8 waves
  const int lm = lane & 15, q = lane >> 4;
  const int m0 = blockIdx.x * 64;
  const int wm = (wv & 1) * 32;                    // rows 0/32
  const int wn = (wv >> 1) * 64;                   // cols 0/64/128/192

  auto stageW = [&](const u16* W, int K, int kc, u16* dst) {
    #pragma unroll
    for (int i = 0; i < 2; i++) {
      int seg = i * 512 + tid;
      int n = seg >> 2, kq = seg & 3;
      async16(W + (size_t)n * K + kc * 32 + kq * 8, dst + seg * 8);
    }
  };
  auto stageA = [&](int kc, u16* dst) {
    if (tid < 256) {
      int r = tid >> 2, kq = tid & 3;
      async16(xb + (size_t)(m0 + r) * 800 + kc * 32 + kq * 8, dst + tid * 8);
    }
  };
  auto stageW4 = [&]() {   // W4b [16][256] -> Wt[1] CONTIGUOUS (lane-linear dest!)
    if (tid < 512) async16(W4b + tid * 8, Wt[1] + tid * 8);
  };
  // operand-swapped epilogue: lane (lm,q) holds rows wm+mi*16+lm, cols wn+ni*16+q*4..+3
  auto epilogue = [&](f32x4 (&acc)[2][4], const float* __restrict__ bias) {
    #pragma unroll
    for (int mi = 0; mi < 2; mi++) {
      int row = wm + mi * 16 + lm;
      #pragma unroll
      for (int ni = 0; ni < 4; ni++) {
        int col = wn + ni * 16 + q * 4;
        float4 bv = *(const float4*)(bias + col);
        float h0 = acc[mi][ni][0] + bv.x; h0 = h0 > 0.0f ? h0 : 0.0f;
        float h1 = acc[mi][ni][1] + bv.y; h1 = h1 > 0.0f ? h1 : 0.0f;
        float h2 = acc[mi][ni][2] + bv.z; h2 = h2 > 0.0f ? h2 : 0.0f;
        float h3 = acc[mi][ni][3] + bv.w; h3 = h3 > 0.0f ? h3 : 0.0f;
        ushort4 o = {f2bf(h0), f2bf(h1), f2bf(h2), f2bf(h3)};
        int kt = col >> 5, cin = col & 31;
        *(ushort4*)(hbuf + kt * 2560 + row * 40 + cin) = o;
      }
    }
  };
  // conflict-free bitpack: wave wv handles kt=wv; lane = row (64 rows = this block's chunk)
  auto ballot_pass = [&](u64* bits) {
    u64 my = 0;
    #pragma unroll
    for (int g = 0; g < 4; g++) {
      ushort4 v0 = *(const ushort4*)(hbuf + wv * 2560 + lane * 40 + g * 8);
      ushort4 v1 = *(const ushort4*)(hbuf + wv * 2560 + lane * 40 + g * 8 + 4);
      u16 s[8] = {v0.x, v0.y, v0.z, v0.w, v1.x, v1.y, v1.z, v1.w};
      #pragma unroll
      for (int j = 0; j < 8; j++) {
        u64 m = __ballot(s[j] != 0);
        if (lane == g * 8 + j) my = m;
      }
    }
    if (lane < 32) bits[(size_t)blockIdx.x * 256 + wv * 32 + lane] = my;
  };

  // ---- layer 1: K=800 ----
  {
    f32x4 acc[2][4] = {};
    stageA(0, At[0]);
    stageW(W1b, 800, 0, Wt[0]);
    for (int kc = 0; kc < 25; kc++) {
      int cur = kc & 1;
      __syncthreads();   // drains this kc's staging (issued one full compute phase ago)
      if (kc < 24) { stageA(kc + 1, At[1 - cur]); stageW(W1b, 800, kc + 1, Wt[1 - cur]); }
      else         { stageW(W2b, 256, 0, Wt[1]); }          // cur=0 at kc=24
      bf16x8 w[4], h[2];
      #pragma unroll
      for (int ni = 0; ni < 4; ni++) w[ni] = *(const bf16x8*)(Wt[cur] + (wn + ni * 16 + lm) * 32 + q * 8);
      #pragma unroll
      for (int mi = 0; mi < 2; mi++) h[mi] = *(const bf16x8*)(At[cur] + (wm + mi * 16 + lm) * 32 + q * 8);
      #pragma unroll
      for (int mi = 0; mi < 2; mi++)
        #pragma unroll
        for (int ni = 0; ni < 4; ni++)
          acc[mi][ni] = __builtin_amdgcn_mfma_f32_16x16x32_bf16(w[ni], h[mi], acc[mi][ni], 0, 0, 0);
    }
    __syncthreads();
    epilogue(acc, b1);
  }
  __syncthreads();
  ballot_pass(bits1);

  // ---- layers 2,3: K=256, A from hbuf ----
  auto layer256 = [&](const u16* Wthis, const u16* Wnext, bool nextIsW4,
                      const float* __restrict__ bias, u64* bits) {
    f32x4 acc[2][4] = {};
    for (int kc = 0; kc < 8; kc++) {
      int cur = (kc & 1) ^ 1;
      __syncthreads();
      if (kc < 7)       stageW(Wthis, 256, kc + 1, Wt[cur ^ 1]);
      else if (nextIsW4) stageW4();                          // cur=0 at kc=7 -> Wt[1]
      else              stageW(Wnext, 256, 0, Wt[cur ^ 1]);
      bf16x8 w[4], h[2];
      #pragma unroll
      for (int ni = 0; ni < 4; ni++) w[ni] = *(const bf16x8*)(Wt[cur] + (wn + ni * 16 + lm) * 32 + q * 8);
      #pragma unroll
      for (int mi = 0; mi < 2; mi++) h[mi] = *(const bf16x8*)(hbuf + kc * 2560 + (wm + mi * 16 + lm) * 40 + q * 8);
      #pragma unroll
      for (int mi = 0; mi < 2; mi++)
        #pragma unroll
        for (int ni = 0; ni < 4; ni++)
          acc[mi][ni] = __builtin_amdgcn_mfma_f32_16x16x32_bf16(w[ni], h[mi], acc[mi][ni], 0, 0, 0);
    }
    __syncthreads();     // all hbuf reads complete before overwrite
    epilogue(acc, bias);
    __syncthreads();
    ballot_pass(bits);
  };
  layer256(W2b, W3b, false, b2, bits2);
  layer256(W3b, W4b, true,  b3, bits3);

  // ---- logits: waves 0..3, 16 rows each; W4 in Wt[1] contiguous [16][256] ----
  if (wv < 4) {
    const int r0 = wv * 16;
    f32x4 acc = {};
    #pragma unroll
    for (int kc = 0; kc < 8; kc++) {
      bf16x8 wf = *(const bf16x8*)(Wt[1] + lm * 256 + kc * 32 + q * 8);
      bf16x8 hf = *(const bf16x8*)(hbuf + kc * 2560 + (r0 + lm) * 40 + q * 8);
      acc = __builtin_amdgcn_mfma_f32_16x16x32_bf16(wf, hf, acc, 0, 0, 0);
    }
    // lane (lm,q): row = r0+lm, classes q*4..q*4+3
    int row = r0 + lm;
    float4 v;
    #pragma unroll
    for (int r = 0; r < 4; r++) {
      int c = q * 4 + r;
      float bv = (c < 10) ? b4[c] : 0.0f;
      v[r] = acc[r] + bv;
    }
    float* Ls = (float*)At;                    // [64][12] fp32
    if (q < 3) *(float4*)(Ls + row * 12 + q * 4) = v;
    size_t ob = (size_t)(m0 + row) * 10;
    if (q < 2) {
      *(float2*)(out + ob + q * 4)     = make_float2(v[0], v[1]);
      *(float2*)(out + ob + q * 4 + 2) = make_float2(v[2], v[3]);
    } else if (q == 2) {
      *(float2*)(out + ob + 8) = make_float2(v[0], v[1]);
    }
  }
  __syncthreads();
  if (wv == 0) {
    const float* Ls = (const float*)At;
    float4 c03 = *(const float4*)(Ls + lane * 12);
    float4 c47 = *(const float4*)(Ls + lane * 12 + 4);
    float2 c89 = *(const float2*)(Ls + lane * 12 + 8);
    float s[10] = {c03.x, c03.y, c03.z, c03.w, c47.x, c47.y, c47.z, c47.w, c89.x, c89.y};
    u64 my = 0;
    #pragma unroll
    for (int c = 0; c < 10; c++) {
      u64 m = __ballot(s[c] > 0.0f);
      if (lane == c) my = m;
    }
    if (lane < 10) bits4[(size_t)blockIdx.x * 10 + lane] = my;
  }
}

// ---------- fused coactivations: grid (88, 16), 32 chunks/block ----------
// tile map i = i0 + a*16 + ti, j = j0 + b*16 + tj:
//   cv reads are 16 consecutive u64 (128 B contiguous -> conflict-free),
//   pv reads broadcast (4 addresses). Was 4-way conflicted at tj*4+b.
__global__ __launch_bounds__(256) void coact_all(
    const u64* __restrict__ bits0, const u64* __restrict__ bits1,
    const u64* __restrict__ bits2, const u64* __restrict__ bits3,
    const u64* __restrict__ bits4, float* __restrict__ out) {
  const int bx = blockIdx.x;
  const u64 *bp, *bc; float* Cm; int FP, FC, i0, j0;
  if (bx < 52)      { bp = bits0; bc = bits1; Cm = out + 327680; FP = 784; FC = 256;
                      i0 = (bx % 13) * 64; j0 = (bx / 13) * 64; }
  else if (bx < 68) { int t = bx - 52; bp = bits1; bc = bits2; Cm = out + 528384; FP = 256; FC = 256;
                      i0 = (t & 3) * 64; j0 = (t >> 2) * 64; }
  else if (bx < 84) { int t = bx - 68; bp = bits2; bc = bits3; Cm = out + 593920; FP = 256; FC = 256;
                      i0 = (t & 3) * 64; j0 = (t >> 2) * 64; }
  else              { int t = bx - 84; bp = bits3; bc = bits4; Cm = out + 659456; FP = 256; FC = 10;
                      i0 = t * 64; j0 = 0; }

  __shared__ u64 Ps[16 * 64];
  __shared__ u64 Cs[16 * 64];
  const int tid = threadIdx.x;
  const int ch0 = blockIdx.y * 32;          // 32 chunks per block
  const int ti = tid >> 4, tj = tid & 15;
  unsigned cnt[4][4] = {};

  for (int s = 0; s < 2; s++) {
    int cb = ch0 + s * 16;
    #pragma unroll
    for (int r = 0; r < 4; r++) {
      int l = r * 256 + tid;
      int c = l >> 6, f = l & 63;
      Ps[l] = (i0 + f < FP) ? bp[(size_t)(cb + c) * FP + i0 + f] : 0ULL;
      Cs[l] = (j0 + f < FC) ? bc[(size_t)(cb + c) * FC + j0 + f] : 0ULL;
    }
    __syncthreads();
    #pragma unroll 4
    for (int c = 0; c < 16; c++) {
      u64 pv[4], cv[4];
      #pragma unroll
      for (int a = 0; a < 4; a++) pv[a] = Ps[c * 64 + a * 16 + ti];
      #pragma unroll
      for (int b = 0; b < 4; b++) cv[b] = Cs[c * 64 + b * 16 + tj];
      #pragma unroll
      for (int a = 0; a < 4; a++)
        #pragma unroll
        for (int b = 0; b < 4; b++)
          cnt[a][b] += (unsigned)__builtin_popcountll(pv[a] & cv[b]);
    }
    __syncthreads();
  }

  #pragma unroll
  for (int a = 0; a < 4; a++) {
    int i = i0 + a * 16 + ti;
    if (i >= FP) continue;
    #pragma unroll
    for (int b = 0; b < 4; b++) {
      int j = j0 + b * 16 + tj;
      if (j < FC) atomicAdd(&Cm[(size_t)i * FC + j], (float)cnt[a][b]);
    }
  }
}

// ---------- launch ----------
extern "C" void kernel_launch(void* const* d_in, const int* in_sizes, int n_in,
                              void* d_out, int out_size, void* d_ws, size_t ws_size,
                              hipStream_t stream) {
  const float* x  = (const float*)d_in[0];
  const float* W1 = (const float*)d_in[1];
  const float* b1 = (const float*)d_in[2];
  const float* W2 = (const float*)d_in[3];
  const float* b2 = (const float*)d_in[4];
  const float* W3 = (const float*)d_in[5];
  const float* b3 = (const float*)d_in[6];
  const float* W4 = (const float*)d_in[7];
  const float* b4 = (const float*)d_in[8];
  float* out = (float*)d_out;

  constexpr size_t O_C0 = 327680, O_END = 662016;

  char* ws = (char*)d_ws;
  u16* xb   = (u16*)(ws);                 // 32768*800*2 = 52428800
  char* p = ws + 52428800;
  u16* w1b  = (u16*)p;  p += (size_t)256 * 800 * 2;
  u16* w2b  = (u16*)p;  p += (size_t)256 * 256 * 2;
  u16* w3b  = (u16*)p;  p += (size_t)256 * 256 * 2;
  u16* w4b  = (u16*)p;  p += (size_t)16 * 256 * 2;
  u64* bits0 = (u64*)p; p += (size_t)512 * 784 * 8;
  u64* bits1 = (u64*)p; p += (size_t)512 * 256 * 8;
  u64* bits2 = (u64*)p; p += (size_t)512 * 256 * 8;
  u64* bits3 = (u64*)p; p += (size_t)512 * 256 * 8;
  u64* bits4 = (u64*)p; p += (size_t)512 * 10 * 8;

  hipMemsetAsync((void*)(out + O_C0), 0, (O_END - O_C0) * sizeof(float), stream);

  convert_all<<<1328, 256, 0, stream>>>(W1, W2, W3, W4, w1b, w2b, w3b, w4b);
  prep_x<<<dim3(13, 512), 256, 0, stream>>>(x, xb, bits0);

  fwd_fused<<<512, 512, 0, stream>>>(xb, w1b, b1, w2b, b2, w3b, b3, w4b, b4,
                                     out, bits1, bits2, bits3, bits4);

  coact_all<<<dim3(88, 16), 256, 0, stream>>>(bits0, bits1, bits2, bits3, bits4, out);
}